// Round 4
// baseline (1383.552 us; speedup 1.0000x reference)
//
#include <hip/hip_runtime.h>

#define NG 128
#define NN 1024
#define KK 16
#define PCAP 8            // flush trigger (checked once per 8-candidate group)
#define PMAX 15           // max pending per lane (7 carry + 8 new)
#define SLOPE 0.01f
#define FINF 3.0e38f

typedef unsigned short u16;

__device__ __forceinline__ float leaky(float v) {
    return v >= 0.0f ? v : SLOPE * v;
}

// Exact top-16 nearest of node i among NN candidates (self excluded).
// Set kept UNSORTED in registers: replace lexicographic-max (d, j), rescan.
// Strict '<' insert + ascending-j scan + evict-largest-j-on-ties == jax top_k set.
__device__ __forceinline__ void knn_scan(const float4* __restrict__ posq,
                                         float* __restrict__ pend_d,
                                         u16* __restrict__ pend_j,
                                         int tid, int i,
                                         u16* __restrict__ idx_out) {
    const float4 me = posq[i];
    float bd[KK];
    int bi[KK];
#pragma unroll
    for (int t = 0; t < KK; ++t) { bd[t] = FINF; bi[t] = 2048 + t; }
    float worst = FINF;
    int wj = 2048 + KK - 1, wslot = KK - 1;
    float T = FINF;
    int cnt = 0;

    for (int j0 = 0; j0 < NN; j0 += 8) {
        float4 p[8];
#pragma unroll
        for (int u = 0; u < 8; ++u) p[u] = posq[j0 + u];
#pragma unroll
        for (int u = 0; u < 8; ++u) {
            const int j = j0 + u;
            float d2 = me.w + p[u].w -
                       2.0f * (me.x * p[u].x + me.y * p[u].y + me.z * p[u].z);
            bool pass = (d2 < T) && (j != i);
            if (pass) {
                pend_d[tid + 256 * cnt] = d2;
                pend_j[tid + 256 * cnt] = (u16)j;
                ++cnt;
            }
        }
        if (__any(cnt >= PCAP)) {
#pragma unroll 1
            for (int s = 0; s < PMAX; ++s) {
                float d = (s < cnt) ? pend_d[tid + 256 * s] : FINF;
                int j = pend_j[tid + 256 * s];
                bool ins = d < worst;
                if (__any(ins)) {
#pragma unroll
                    for (int t = 0; t < KK; ++t) {
                        bool hit = ins && (t == wslot);
                        bd[t] = hit ? d : bd[t];
                        bi[t] = hit ? j : bi[t];
                    }
                    worst = bd[0]; wj = bi[0]; wslot = 0;
#pragma unroll
                    for (int t = 1; t < KK; ++t) {
                        bool gt = (bd[t] > worst) || (bd[t] == worst && bi[t] > wj);
                        worst = gt ? bd[t] : worst;
                        wj    = gt ? bi[t] : wj;
                        wslot = gt ? t    : wslot;
                    }
                }
            }
            cnt = 0;
            T = worst;
        }
    }
#pragma unroll 1
    for (int s = 0; s < PCAP; ++s) {   // final flush: cnt <= 7 here
        float d = (s < cnt) ? pend_d[tid + 256 * s] : FINF;
        int j = pend_j[tid + 256 * s];
        bool ins = d < worst;
        if (__any(ins)) {
#pragma unroll
            for (int t = 0; t < KK; ++t) {
                bool hit = ins && (t == wslot);
                bd[t] = hit ? d : bd[t];
                bi[t] = hit ? j : bi[t];
            }
            worst = bd[0]; wj = bi[0]; wslot = 0;
#pragma unroll
            for (int t = 1; t < KK; ++t) {
                bool gt = (bd[t] > worst) || (bd[t] == worst && bi[t] > wj);
                worst = gt ? bd[t] : worst;
                wj    = gt ? bi[t] : wj;
                wslot = gt ? t    : wslot;
            }
        }
    }
#pragma unroll
    for (int t = 0; t < KK; ++t) idx_out[t] = (u16)bi[t];
}

// ---------------- kNN on xyz -> idx ------------------------------------------------
__global__ __launch_bounds__(256) void knn1(
    const float* __restrict__ x,    // [NG*NN*3]
    u16* __restrict__ idx)          // [NG*NN*16]
{
    __shared__ float4 posq[NN];                 // 16 KB
    __shared__ float pend_d[256 * PMAX];        // 15 KB
    __shared__ u16 pend_j[256 * PMAX];          // 7.5 KB

    const int g = blockIdx.x >> 2;
    const int chunk = blockIdx.x & 3;
    const int tid = threadIdx.x;

    for (int n = tid; n < NN; n += 256) {
        const float* xp = x + (size_t)(g * NN + n) * 3;
        float px = xp[0], py = xp[1], pz = xp[2];
        posq[n] = make_float4(px, py, pz, px * px + py * py + pz * pz);
    }
    __syncthreads();

    const int i = chunk * 256 + tid;
    knn_scan(posq, pend_d, pend_j, tid, i, idx + (size_t)(g * NN + i) * KK);
}

// ---------------- kNN on h1[:, :3] -> idx ------------------------------------------
__global__ __launch_bounds__(256) void knn2(
    const float* __restrict__ h1,   // [NG*NN*16]
    u16* __restrict__ idx)          // [NG*NN*16]
{
    __shared__ float4 posq[NN];
    __shared__ float pend_d[256 * PMAX];
    __shared__ u16 pend_j[256 * PMAX];

    const int g = blockIdx.x >> 2;
    const int chunk = blockIdx.x & 3;
    const int tid = threadIdx.x;

    for (int n = tid; n < NN; n += 256) {
        const float4 a = *(const float4*)(h1 + (size_t)(g * NN + n) * 16);
        posq[n] = make_float4(a.x, a.y, a.z, a.x * a.x + a.y * a.y + a.z * a.z);
    }
    __syncthreads();

    const int i = chunk * 256 + tid;
    knn_scan(posq, pend_d, pend_j, tid, i, idx + (size_t)(g * NN + i) * KK);
}

// ---------------- EdgeConv 1: [6->16->16], sum over k ------------------------------
__global__ __launch_bounds__(256) void conv1(
    const float* __restrict__ x,    // [NG*NN*3]
    const u16* __restrict__ idx,    // [NG*NN*16]
    const float* __restrict__ W1,   // [6*16]
    const float* __restrict__ b1,   // [16]
    const float* __restrict__ W2,   // [16*16]
    const float* __restrict__ b2,   // [16]
    float* __restrict__ h1)         // [NG*NN*16]
{
    __shared__ float4 posq[NN];
    __shared__ float w1[6 * 16];
    __shared__ float w2[16 * 16];
    __shared__ float bb1[16], bb2[16];

    const int g = blockIdx.x >> 2;
    const int chunk = blockIdx.x & 3;
    const int tid = threadIdx.x;

    if (tid < 96) w1[tid] = W1[tid];
    w2[tid] = W2[tid];
    if (tid < 16) { bb1[tid] = b1[tid]; bb2[tid] = b2[tid]; }

    for (int n = tid; n < NN; n += 256) {
        const float* xp = x + (size_t)(g * NN + n) * 3;
        float px = xp[0], py = xp[1], pz = xp[2];
        posq[n] = make_float4(px, py, pz, 0.0f);
    }
    __syncthreads();

    const int i = chunk * 256 + tid;
    const float4 me = posq[i];
    const u16* my_idx = idx + (size_t)(g * NN + i) * KK;

    float acc[16];
#pragma unroll
    for (int o = 0; o < 16; ++o) acc[o] = 0.0f;

#pragma unroll 1
    for (int t = 0; t < KK; ++t) {
        const int j = my_idx[t];
        float4 pj = posq[j];
        float in3 = pj.x - me.x, in4 = pj.y - me.y, in5 = pj.z - me.z;
        float m1[16];
#pragma unroll
        for (int o = 0; o < 16; ++o) {
            float v = bb1[o];
            v += me.x * w1[0 * 16 + o];
            v += me.y * w1[1 * 16 + o];
            v += me.z * w1[2 * 16 + o];
            v += in3 * w1[3 * 16 + o];
            v += in4 * w1[4 * 16 + o];
            v += in5 * w1[5 * 16 + o];
            m1[o] = leaky(v);
        }
#pragma unroll
        for (int o = 0; o < 16; ++o) {
            float v = bb2[o];
#pragma unroll
            for (int f = 0; f < 16; ++f) v += m1[f] * w2[f * 16 + o];
            acc[o] += leaky(v);
        }
    }

    float4* out = (float4*)(h1 + (size_t)(g * NN + i) * 16);
    out[0] = make_float4(acc[0], acc[1], acc[2], acc[3]);
    out[1] = make_float4(acc[4], acc[5], acc[6], acc[7]);
    out[2] = make_float4(acc[8], acc[9], acc[10], acc[11]);
    out[3] = make_float4(acc[12], acc[13], acc[14], acc[15]);
}

// ---------- EdgeConv 2 [32->16->16] + post-MLP [35->16->16] + block-partial pool ----
__global__ __launch_bounds__(256) void conv2_post(
    const float* __restrict__ x,    // [NG*NN*3]
    const float* __restrict__ h1,   // [NG*NN*16]
    const u16* __restrict__ idx,    // [NG*NN*16]
    const float* __restrict__ W1,   // [32*16]
    const float* __restrict__ b1,   // [16]
    const float* __restrict__ W2,   // [16*16]
    const float* __restrict__ b2,   // [16]
    const float* __restrict__ Wp1, const float* __restrict__ bp1,   // [35*16],[16]
    const float* __restrict__ Wp2, const float* __restrict__ bp2,   // [16*16],[16]
    float* __restrict__ partial)    // [512*48]  (per-block: min16,max16,sum16)
{
    __shared__ float w1[32 * 16];
    __shared__ float w2[16 * 16];
    __shared__ float wp1[35 * 16];
    __shared__ float wp2[16 * 16];
    __shared__ float bb1[16], bb2[16], sbp1[16], sbp2[16];
    __shared__ float red[3][4][16];

    const int g = blockIdx.x >> 2;
    const int chunk = blockIdx.x & 3;
    const int tid = threadIdx.x;

    w1[tid] = W1[tid];
    w1[256 + tid] = W1[256 + tid];
    w2[tid] = W2[tid];
    wp2[tid] = Wp2[tid];
    for (int t = tid; t < 560; t += 256) wp1[t] = Wp1[t];
    if (tid < 16) {
        bb1[tid] = b1[tid]; bb2[tid] = b2[tid];
        sbp1[tid] = bp1[tid]; sbp2[tid] = bp2[tid];
    }
    __syncthreads();

    const int i = chunk * 256 + tid;
    const u16* my_idx = idx + (size_t)(g * NN + i) * KK;

    const float4* mp4 = (const float4*)(h1 + (size_t)(g * NN + i) * 16);
    float4 a0 = mp4[0], a1 = mp4[1], a2 = mp4[2], a3 = mp4[3];
    float xi[16] = {a0.x, a0.y, a0.z, a0.w, a1.x, a1.y, a1.z, a1.w,
                    a2.x, a2.y, a2.z, a2.w, a3.x, a3.y, a3.z, a3.w};

    float acc[16];
#pragma unroll
    for (int o = 0; o < 16; ++o) acc[o] = 0.0f;

#pragma unroll 1
    for (int t = 0; t < KK; ++t) {
        const int j = my_idx[t];
        const float4* jp4 = (const float4*)(h1 + (size_t)(g * NN + j) * 16);
        float4 j0 = jp4[0], j1 = jp4[1], j2 = jp4[2], j3 = jp4[3];
        float xj[16] = {j0.x, j0.y, j0.z, j0.w, j1.x, j1.y, j1.z, j1.w,
                        j2.x, j2.y, j2.z, j2.w, j3.x, j3.y, j3.z, j3.w};
        float m1[16];
#pragma unroll
        for (int o = 0; o < 16; ++o) {
            float v = bb1[o];
#pragma unroll
            for (int f = 0; f < 16; ++f) v += xi[f] * w1[f * 16 + o];
#pragma unroll
            for (int f = 0; f < 16; ++f) v += (xj[f] - xi[f]) * w1[(16 + f) * 16 + o];
            m1[o] = leaky(v);
        }
#pragma unroll
        for (int o = 0; o < 16; ++o) {
            float v = bb2[o];
#pragma unroll
            for (int f = 0; f < 16; ++f) v += m1[f] * w2[f * 16 + o];
            acc[o] += leaky(v);
        }
    }

    // post-MLP: feat = [x(3), h1(16), h2(16)]
    float feat[35];
    {
        const float* xp = x + (size_t)(g * NN + i) * 3;
        feat[0] = xp[0]; feat[1] = xp[1]; feat[2] = xp[2];
#pragma unroll
        for (int f = 0; f < 16; ++f) feat[3 + f] = xi[f];
#pragma unroll
        for (int f = 0; f < 16; ++f) feat[19 + f] = acc[f];
    }
    float p1[16];
#pragma unroll
    for (int o = 0; o < 16; ++o) {
        float v = sbp1[o];
#pragma unroll
        for (int f = 0; f < 35; ++f) v += feat[f] * wp1[f * 16 + o];
        p1[o] = leaky(v);
    }
    float mn[16], mx[16], sm[16];
#pragma unroll
    for (int o = 0; o < 16; ++o) {
        float v = sbp2[o];
#pragma unroll
        for (int f = 0; f < 16; ++f) v += p1[f] * wp2[f * 16 + o];
        float p2 = leaky(v);
        mn[o] = p2; mx[o] = p2; sm[o] = p2;
    }

#pragma unroll
    for (int off = 32; off >= 1; off >>= 1) {
#pragma unroll
        for (int o = 0; o < 16; ++o) {
            mn[o] = fminf(mn[o], __shfl_xor(mn[o], off));
            mx[o] = fmaxf(mx[o], __shfl_xor(mx[o], off));
            sm[o] += __shfl_xor(sm[o], off);
        }
    }
    const int wave = tid >> 6;
    const int lane = tid & 63;
    if (lane == 0) {
#pragma unroll
        for (int o = 0; o < 16; ++o) {
            red[0][wave][o] = mn[o];
            red[1][wave][o] = mx[o];
            red[2][wave][o] = sm[o];
        }
    }
    __syncthreads();

    if (tid < 48) {
        const int stat = tid >> 4, o = tid & 15;
        float v;
        if (stat == 0)
            v = fminf(fminf(red[0][0][o], red[0][1][o]), fminf(red[0][2][o], red[0][3][o]));
        else if (stat == 1)
            v = fmaxf(fmaxf(red[1][0][o], red[1][1][o]), fmaxf(red[1][2][o], red[1][3][o]));
        else
            v = red[2][0][o] + red[2][1][o] + red[2][2][o] + red[2][3][o];
        partial[blockIdx.x * 48 + tid] = v;
    }
}

// -------- Finalize: combine 4 block-partials per graph + readout [48->128->10] -----
__global__ __launch_bounds__(128) void finalize(
    const float* __restrict__ partial,   // [512*48]
    const float* __restrict__ Wr1, const float* __restrict__ br1,   // [48*128],[128]
    const float* __restrict__ Wr2, const float* __restrict__ br2,   // [128*10],[10]
    float* __restrict__ out)             // [NG*10]
{
    __shared__ float pooled[48];
    __shared__ float hidden[128];

    const int g = blockIdx.x;
    const int tid = threadIdx.x;

    if (tid < 48) {
        const int stat = tid >> 4;
        float a = partial[(g * 4 + 0) * 48 + tid];
        float b = partial[(g * 4 + 1) * 48 + tid];
        float c = partial[(g * 4 + 2) * 48 + tid];
        float d = partial[(g * 4 + 3) * 48 + tid];
        float v;
        if (stat == 0)      v = fminf(fminf(a, b), fminf(c, d));
        else if (stat == 1) v = fmaxf(fmaxf(a, b), fmaxf(c, d));
        else                v = (a + b + c + d) * (1.0f / NN);
        pooled[tid] = v;
    }
    __syncthreads();

    {
        float v = br1[tid];
#pragma unroll
        for (int f = 0; f < 48; ++f) v += pooled[f] * Wr1[f * 128 + tid];
        hidden[tid] = leaky(v);
    }
    __syncthreads();

    if (tid < 10) {
        float v = br2[tid];
#pragma unroll
        for (int f = 0; f < 128; ++f) v += hidden[f] * Wr2[f * 10 + tid];
        out[g * 10 + tid] = v;
    }
}

extern "C" void kernel_launch(void* const* d_in, const int* in_sizes, int n_in,
                              void* d_out, int out_size, void* d_ws, size_t ws_size,
                              hipStream_t stream) {
    const float* x   = (const float*)d_in[0];
    const float* W1a = (const float*)d_in[2];
    const float* b1a = (const float*)d_in[3];
    const float* W2a = (const float*)d_in[4];
    const float* b2a = (const float*)d_in[5];
    const float* W1b = (const float*)d_in[6];
    const float* b1b = (const float*)d_in[7];
    const float* W2b = (const float*)d_in[8];
    const float* b2b = (const float*)d_in[9];
    const float* Wp1 = (const float*)d_in[10];
    const float* bp1 = (const float*)d_in[11];
    const float* Wp2 = (const float*)d_in[12];
    const float* bp2 = (const float*)d_in[13];
    const float* Wr1 = (const float*)d_in[14];
    const float* br1 = (const float*)d_in[15];
    const float* Wr2 = (const float*)d_in[16];
    const float* br2 = (const float*)d_in[17];
    float* out = (float*)d_out;

    float* h1 = (float*)d_ws;                         // 8 MB
    u16* idx = (u16*)(h1 + (size_t)NG * NN * 16);     // 4 MB (reused by both kNNs)
    float* partial = (float*)(idx + (size_t)NG * NN * KK);  // 512*48 floats

    knn1<<<NG * 4, 256, 0, stream>>>(x, idx);
    conv1<<<NG * 4, 256, 0, stream>>>(x, idx, W1a, b1a, W2a, b2a, h1);
    knn2<<<NG * 4, 256, 0, stream>>>(h1, idx);
    conv2_post<<<NG * 4, 256, 0, stream>>>(x, h1, idx, W1b, b1b, W2b, b2b,
                                           Wp1, bp1, Wp2, bp2, partial);
    finalize<<<NG, 128, 0, stream>>>(partial, Wr1, br1, Wr2, br2, out);
}

// Round 5
// 1222.880 us; speedup vs baseline: 1.1314x; 1.1314x over previous
//
#include <hip/hip_runtime.h>

#define NG 128
#define NN 1024
#define KK 16
#define PCAP 16           // flush trigger (checked once per 8-candidate group)
#define PMAX 23           // max pending per lane (15 carry + 8 new)
#define SLOPE 0.01f
#define FINF 3.0e38f

typedef unsigned short u16;

__device__ __forceinline__ float leaky(float v) {
    return v >= 0.0f ? v : SLOPE * v;
}

// branchless stable sorted insert (ascending by d; ties keep existing = earlier j)
__device__ __forceinline__ void sorted_insert(float (&bd)[KK], int (&bi)[KK],
                                              float d, int j) {
    bool c[KK];
#pragma unroll
    for (int t = 0; t < KK; ++t) c[t] = d < bd[t];
#pragma unroll
    for (int t = KK - 1; t >= 1; --t) {
        bd[t] = c[t] ? (c[t - 1] ? bd[t - 1] : d) : bd[t];
        bi[t] = c[t] ? (c[t - 1] ? bi[t - 1] : j) : bi[t];
    }
    bd[0] = c[0] ? d : bd[0];
    bi[0] = c[0] ? j : bi[0];
}

// Exact top-16 nearest of node i among NN candidates (self excluded).
// bd/bi sorted ascending, registers only. pend: per-lane LDS columns.
__device__ __forceinline__ void knn_scan(const float4* __restrict__ posq,
                                         float* __restrict__ pend_d,
                                         u16* __restrict__ pend_j,
                                         int tid, int i,
                                         u16* __restrict__ idx_out) {
    const float4 meq = posq[i];
    const float mex = -2.0f * meq.x, mey = -2.0f * meq.y, mez = -2.0f * meq.z;
    const float mew = meq.w;
    float bd[KK];
    int bi[KK];
#pragma unroll
    for (int t = 0; t < KK; ++t) { bd[t] = FINF; bi[t] = 0; }
    float T = FINF;
    int cnt = 0;

    for (int j0 = 0; j0 < NN; j0 += 8) {
        float4 p[8];
#pragma unroll
        for (int u = 0; u < 8; ++u) p[u] = posq[j0 + u];
#pragma unroll
        for (int u = 0; u < 8; ++u) {
            const int j = j0 + u;
            float d2 = fmaf(mex, p[u].x, fmaf(mey, p[u].y,
                          fmaf(mez, p[u].z, mew + p[u].w)));
            bool pass = (d2 < T) && (j != i);
            if (pass) {
                pend_d[tid + 256 * cnt] = d2;
                pend_j[tid + 256 * cnt] = (u16)j;
                ++cnt;
            }
        }
        if (__any(cnt >= PCAP)) {
#pragma unroll 1
            for (int s = 0; s < PMAX; ++s) {
                float d = (s < cnt) ? pend_d[tid + 256 * s] : FINF;
                int j = pend_j[tid + 256 * s];
                if (__any(d < bd[KK - 1])) sorted_insert(bd, bi, d, j);
            }
            cnt = 0;
            T = bd[KK - 1];
        }
    }
#pragma unroll 1
    for (int s = 0; s < PCAP; ++s) {   // final flush: all lanes have cnt <= 15
        float d = (s < cnt) ? pend_d[tid + 256 * s] : FINF;
        int j = pend_j[tid + 256 * s];
        if (__any(d < bd[KK - 1])) sorted_insert(bd, bi, d, j);
    }
#pragma unroll
    for (int t = 0; t < KK; ++t) idx_out[t] = (u16)bi[t];
}

// ---------------- kNN on xyz -> idx ------------------------------------------------
__global__ __launch_bounds__(256) void knn1(
    const float* __restrict__ x,    // [NG*NN*3]
    u16* __restrict__ idx)          // [NG*NN*16]
{
    __shared__ float4 posq[NN];              // 16 KB
    __shared__ float pend_d[256 * PMAX];     // 23 KB
    __shared__ u16 pend_j[256 * PMAX];       // 11.5 KB

    const int g = blockIdx.x >> 2;
    const int chunk = blockIdx.x & 3;
    const int tid = threadIdx.x;

    for (int n = tid; n < NN; n += 256) {
        const float* xp = x + (size_t)(g * NN + n) * 3;
        float px = xp[0], py = xp[1], pz = xp[2];
        posq[n] = make_float4(px, py, pz, px * px + py * py + pz * pz);
    }
    __syncthreads();

    const int i = chunk * 256 + tid;
    knn_scan(posq, pend_d, pend_j, tid, i, idx + (size_t)(g * NN + i) * KK);
}

// ---------------- kNN on h1[:, :3] -> idx ------------------------------------------
__global__ __launch_bounds__(256) void knn2(
    const float* __restrict__ h1,   // [NG*NN*16]
    u16* __restrict__ idx)          // [NG*NN*16]
{
    __shared__ float4 posq[NN];
    __shared__ float pend_d[256 * PMAX];
    __shared__ u16 pend_j[256 * PMAX];

    const int g = blockIdx.x >> 2;
    const int chunk = blockIdx.x & 3;
    const int tid = threadIdx.x;

    for (int n = tid; n < NN; n += 256) {
        const float4 a = *(const float4*)(h1 + (size_t)(g * NN + n) * 16);
        posq[n] = make_float4(a.x, a.y, a.z, a.x * a.x + a.y * a.y + a.z * a.z);
    }
    __syncthreads();

    const int i = chunk * 256 + tid;
    knn_scan(posq, pend_d, pend_j, tid, i, idx + (size_t)(g * NN + i) * KK);
}

// ---------------- EdgeConv 1: [6->16->16], sum over k ------------------------------
__global__ __launch_bounds__(256) void conv1(
    const float* __restrict__ x,    // [NG*NN*3]
    const u16* __restrict__ idx,    // [NG*NN*16]
    const float* __restrict__ W1,   // [6*16]
    const float* __restrict__ b1,   // [16]
    const float* __restrict__ W2,   // [16*16]
    const float* __restrict__ b2,   // [16]
    float* __restrict__ h1)         // [NG*NN*16]
{
    __shared__ float4 posq[NN];
    __shared__ float w1[6 * 16];
    __shared__ float w2[16 * 16];
    __shared__ float bb1[16], bb2[16];

    const int g = blockIdx.x >> 2;
    const int chunk = blockIdx.x & 3;
    const int tid = threadIdx.x;

    if (tid < 96) w1[tid] = W1[tid];
    w2[tid] = W2[tid];
    if (tid < 16) { bb1[tid] = b1[tid]; bb2[tid] = b2[tid]; }

    for (int n = tid; n < NN; n += 256) {
        const float* xp = x + (size_t)(g * NN + n) * 3;
        posq[n] = make_float4(xp[0], xp[1], xp[2], 0.0f);
    }
    __syncthreads();

    const int i = chunk * 256 + tid;
    const float4 me = posq[i];
    const u16* my_idx = idx + (size_t)(g * NN + i) * KK;

    // s1[o] = b1[o] + sum_f xi_f * (W1[f,o] - W1[3+f,o])
    float s1[16];
#pragma unroll
    for (int o = 0; o < 16; ++o) {
        s1[o] = bb1[o]
              + me.x * (w1[0 * 16 + o] - w1[3 * 16 + o])
              + me.y * (w1[1 * 16 + o] - w1[4 * 16 + o])
              + me.z * (w1[2 * 16 + o] - w1[5 * 16 + o]);
    }

    float acc[16];
#pragma unroll
    for (int o = 0; o < 16; ++o) acc[o] = 0.0f;

#pragma unroll 1
    for (int t = 0; t < KK; ++t) {
        const int j = my_idx[t];
        float4 pj = posq[j];
        float m1[16];
#pragma unroll
        for (int o = 0; o < 16; ++o) {
            float v = s1[o];
            v += pj.x * w1[3 * 16 + o];
            v += pj.y * w1[4 * 16 + o];
            v += pj.z * w1[5 * 16 + o];
            m1[o] = leaky(v);
        }
#pragma unroll
        for (int o = 0; o < 16; ++o) {
            float v = bb2[o];
#pragma unroll
            for (int f = 0; f < 16; ++f) v += m1[f] * w2[f * 16 + o];
            acc[o] += leaky(v);
        }
    }

    float4* out = (float4*)(h1 + (size_t)(g * NN + i) * 16);
    out[0] = make_float4(acc[0], acc[1], acc[2], acc[3]);
    out[1] = make_float4(acc[4], acc[5], acc[6], acc[7]);
    out[2] = make_float4(acc[8], acc[9], acc[10], acc[11]);
    out[3] = make_float4(acc[12], acc[13], acc[14], acc[15]);
}

// ---------- EdgeConv 2 [32->16->16] + post-MLP [35->16->16] + block-partial pool ----
// h1 tile staged in LDS: kills the L2-thrashing gather amplification.
__global__ __launch_bounds__(256, 2) void conv2_post(
    const float* __restrict__ x,    // [NG*NN*3]
    const float* __restrict__ h1,   // [NG*NN*16]
    const u16* __restrict__ idx,    // [NG*NN*16]
    const float* __restrict__ W1,   // [32*16]
    const float* __restrict__ b1,   // [16]
    const float* __restrict__ W2,   // [16*16]
    const float* __restrict__ b2,   // [16]
    const float* __restrict__ Wp1, const float* __restrict__ bp1,   // [35*16],[16]
    const float* __restrict__ Wp2, const float* __restrict__ bp2,   // [16*16],[16]
    float* __restrict__ partial)    // [512*48]  (per-block: min16,max16,sum16)
{
    __shared__ float4 tile4[NN * 4];        // 64 KB: full h1 tile of this graph
    __shared__ float w1hi[16 * 16];         // W1[16+f, o]
    __shared__ float wd[16 * 16];           // W1[f,o] - W1[16+f,o]
    __shared__ float w2[16 * 16];
    __shared__ float wp1[35 * 16];
    __shared__ float wp2[16 * 16];
    __shared__ float bb1[16], bb2[16], sbp1[16], sbp2[16];
    __shared__ float red[3][4][16];

    const int g = blockIdx.x >> 2;
    const int chunk = blockIdx.x & 3;
    const int tid = threadIdx.x;

    wd[tid]   = W1[tid] - W1[256 + tid];
    w1hi[tid] = W1[256 + tid];
    w2[tid] = W2[tid];
    wp2[tid] = Wp2[tid];
    for (int t = tid; t < 560; t += 256) wp1[t] = Wp1[t];
    if (tid < 16) {
        bb1[tid] = b1[tid]; bb2[tid] = b2[tid];
        sbp1[tid] = bp1[tid]; sbp2[tid] = bp2[tid];
    }

    const float4* src4 = (const float4*)(h1 + (size_t)g * NN * 16);
    for (int t = tid; t < NN * 4; t += 256) tile4[t] = src4[t];
    __syncthreads();

    const int i = chunk * 256 + tid;
    const u16* my_idx = idx + (size_t)(g * NN + i) * KK;

    // own features from LDS
    float4 a0 = tile4[i * 4 + 0], a1 = tile4[i * 4 + 1];
    float4 a2 = tile4[i * 4 + 2], a3 = tile4[i * 4 + 3];

    // s1[o] = b1[o] + sum_f xi_f * wd[f,o]
    float s1[16];
#pragma unroll
    for (int o = 0; o < 16; ++o) {
        float v = bb1[o];
        v += a0.x * wd[0 * 16 + o];  v += a0.y * wd[1 * 16 + o];
        v += a0.z * wd[2 * 16 + o];  v += a0.w * wd[3 * 16 + o];
        v += a1.x * wd[4 * 16 + o];  v += a1.y * wd[5 * 16 + o];
        v += a1.z * wd[6 * 16 + o];  v += a1.w * wd[7 * 16 + o];
        v += a2.x * wd[8 * 16 + o];  v += a2.y * wd[9 * 16 + o];
        v += a2.z * wd[10 * 16 + o]; v += a2.w * wd[11 * 16 + o];
        v += a3.x * wd[12 * 16 + o]; v += a3.y * wd[13 * 16 + o];
        v += a3.z * wd[14 * 16 + o]; v += a3.w * wd[15 * 16 + o];
        s1[o] = v;
    }

    float acc[16];
#pragma unroll
    for (int o = 0; o < 16; ++o) acc[o] = 0.0f;

#pragma unroll 1
    for (int t = 0; t < KK; ++t) {
        const int j = my_idx[t];
        float4 j0 = tile4[j * 4 + 0], j1 = tile4[j * 4 + 1];
        float4 j2 = tile4[j * 4 + 2], j3 = tile4[j * 4 + 3];
        float m1[16];
#pragma unroll
        for (int o = 0; o < 16; ++o) {
            float v = s1[o];
            v += j0.x * w1hi[0 * 16 + o];  v += j0.y * w1hi[1 * 16 + o];
            v += j0.z * w1hi[2 * 16 + o];  v += j0.w * w1hi[3 * 16 + o];
            v += j1.x * w1hi[4 * 16 + o];  v += j1.y * w1hi[5 * 16 + o];
            v += j1.z * w1hi[6 * 16 + o];  v += j1.w * w1hi[7 * 16 + o];
            v += j2.x * w1hi[8 * 16 + o];  v += j2.y * w1hi[9 * 16 + o];
            v += j2.z * w1hi[10 * 16 + o]; v += j2.w * w1hi[11 * 16 + o];
            v += j3.x * w1hi[12 * 16 + o]; v += j3.y * w1hi[13 * 16 + o];
            v += j3.z * w1hi[14 * 16 + o]; v += j3.w * w1hi[15 * 16 + o];
            m1[o] = leaky(v);
        }
#pragma unroll
        for (int o = 0; o < 16; ++o) {
            float v = bb2[o];
#pragma unroll
            for (int f = 0; f < 16; ++f) v += m1[f] * w2[f * 16 + o];
            acc[o] += leaky(v);
        }
    }

    // post-MLP: p1 = leaky(bp1 + x*Wp1[0:3] + xi*Wp1[3:19] + acc*Wp1[19:35])
    const float* xp = x + (size_t)(g * NN + i) * 3;
    const float x0 = xp[0], x1 = xp[1], x2 = xp[2];
    float p1[16];
#pragma unroll
    for (int o = 0; o < 16; ++o) {
        float v = sbp1[o];
        v += x0 * wp1[0 * 16 + o];
        v += x1 * wp1[1 * 16 + o];
        v += x2 * wp1[2 * 16 + o];
        v += a0.x * wp1[3 * 16 + o];   v += a0.y * wp1[4 * 16 + o];
        v += a0.z * wp1[5 * 16 + o];   v += a0.w * wp1[6 * 16 + o];
        v += a1.x * wp1[7 * 16 + o];   v += a1.y * wp1[8 * 16 + o];
        v += a1.z * wp1[9 * 16 + o];   v += a1.w * wp1[10 * 16 + o];
        v += a2.x * wp1[11 * 16 + o];  v += a2.y * wp1[12 * 16 + o];
        v += a2.z * wp1[13 * 16 + o];  v += a2.w * wp1[14 * 16 + o];
        v += a3.x * wp1[15 * 16 + o];  v += a3.y * wp1[16 * 16 + o];
        v += a3.z * wp1[17 * 16 + o];  v += a3.w * wp1[18 * 16 + o];
#pragma unroll
        for (int f = 0; f < 16; ++f) v += acc[f] * wp1[(19 + f) * 16 + o];
        p1[o] = leaky(v);
    }

    float mn[16], mx[16], sm[16];
#pragma unroll
    for (int o = 0; o < 16; ++o) {
        float v = sbp2[o];
#pragma unroll
        for (int f = 0; f < 16; ++f) v += p1[f] * wp2[f * 16 + o];
        float p2 = leaky(v);
        mn[o] = p2; mx[o] = p2; sm[o] = p2;
    }

#pragma unroll
    for (int off = 32; off >= 1; off >>= 1) {
#pragma unroll
        for (int o = 0; o < 16; ++o) {
            mn[o] = fminf(mn[o], __shfl_xor(mn[o], off));
            mx[o] = fmaxf(mx[o], __shfl_xor(mx[o], off));
            sm[o] += __shfl_xor(sm[o], off);
        }
    }
    const int wave = tid >> 6;
    const int lane = tid & 63;
    if (lane == 0) {
#pragma unroll
        for (int o = 0; o < 16; ++o) {
            red[0][wave][o] = mn[o];
            red[1][wave][o] = mx[o];
            red[2][wave][o] = sm[o];
        }
    }
    __syncthreads();

    if (tid < 48) {
        const int stat = tid >> 4, o = tid & 15;
        float v;
        if (stat == 0)
            v = fminf(fminf(red[0][0][o], red[0][1][o]), fminf(red[0][2][o], red[0][3][o]));
        else if (stat == 1)
            v = fmaxf(fmaxf(red[1][0][o], red[1][1][o]), fmaxf(red[1][2][o], red[1][3][o]));
        else
            v = red[2][0][o] + red[2][1][o] + red[2][2][o] + red[2][3][o];
        partial[blockIdx.x * 48 + tid] = v;
    }
}

// -------- Finalize: combine 4 block-partials per graph + readout [48->128->10] -----
__global__ __launch_bounds__(128) void finalize(
    const float* __restrict__ partial,   // [512*48]
    const float* __restrict__ Wr1, const float* __restrict__ br1,   // [48*128],[128]
    const float* __restrict__ Wr2, const float* __restrict__ br2,   // [128*10],[10]
    float* __restrict__ out)             // [NG*10]
{
    __shared__ float pooled[48];
    __shared__ float hidden[128];

    const int g = blockIdx.x;
    const int tid = threadIdx.x;

    if (tid < 48) {
        const int stat = tid >> 4;
        float a = partial[(g * 4 + 0) * 48 + tid];
        float b = partial[(g * 4 + 1) * 48 + tid];
        float c = partial[(g * 4 + 2) * 48 + tid];
        float d = partial[(g * 4 + 3) * 48 + tid];
        float v;
        if (stat == 0)      v = fminf(fminf(a, b), fminf(c, d));
        else if (stat == 1) v = fmaxf(fmaxf(a, b), fmaxf(c, d));
        else                v = (a + b + c + d) * (1.0f / NN);
        pooled[tid] = v;
    }
    __syncthreads();

    {
        float v = br1[tid];
#pragma unroll
        for (int f = 0; f < 48; ++f) v += pooled[f] * Wr1[f * 128 + tid];
        hidden[tid] = leaky(v);
    }
    __syncthreads();

    if (tid < 10) {
        float v = br2[tid];
#pragma unroll
        for (int f = 0; f < 128; ++f) v += hidden[f] * Wr2[f * 10 + tid];
        out[g * 10 + tid] = v;
    }
}

extern "C" void kernel_launch(void* const* d_in, const int* in_sizes, int n_in,
                              void* d_out, int out_size, void* d_ws, size_t ws_size,
                              hipStream_t stream) {
    const float* x   = (const float*)d_in[0];
    const float* W1a = (const float*)d_in[2];
    const float* b1a = (const float*)d_in[3];
    const float* W2a = (const float*)d_in[4];
    const float* b2a = (const float*)d_in[5];
    const float* W1b = (const float*)d_in[6];
    const float* b1b = (const float*)d_in[7];
    const float* W2b = (const float*)d_in[8];
    const float* b2b = (const float*)d_in[9];
    const float* Wp1 = (const float*)d_in[10];
    const float* bp1 = (const float*)d_in[11];
    const float* Wp2 = (const float*)d_in[12];
    const float* bp2 = (const float*)d_in[13];
    const float* Wr1 = (const float*)d_in[14];
    const float* br1 = (const float*)d_in[15];
    const float* Wr2 = (const float*)d_in[16];
    const float* br2 = (const float*)d_in[17];
    float* out = (float*)d_out;

    float* h1 = (float*)d_ws;                         // 8 MB
    u16* idx = (u16*)(h1 + (size_t)NG * NN * 16);     // 4 MB (reused by both kNNs)
    float* partial = (float*)(idx + (size_t)NG * NN * KK);  // 512*48 floats

    knn1<<<NG * 4, 256, 0, stream>>>(x, idx);
    conv1<<<NG * 4, 256, 0, stream>>>(x, idx, W1a, b1a, W2a, b2a, h1);
    knn2<<<NG * 4, 256, 0, stream>>>(h1, idx);
    conv2_post<<<NG * 4, 256, 0, stream>>>(x, h1, idx, W1b, b1b, W2b, b2b,
                                           Wp1, bp1, Wp2, bp2, partial);
    finalize<<<NG, 128, 0, stream>>>(partial, Wr1, br1, Wr2, br2, out);
}

// Round 7
// 983.115 us; speedup vs baseline: 1.4073x; 1.2439x over previous
//
#include <hip/hip_runtime.h>

#define NG 128
#define NN 1024
#define KK 16
#define PCAP 16           // flush trigger (checked once per 8-candidate group)
#define PMAX 23           // max pending per lane (15 carry + 8 new)
#define SLOPE 0.01f
#define FINF 3.0e38f

typedef unsigned short u16;

__device__ __forceinline__ float leaky(float v) {
    return v >= 0.0f ? v : SLOPE * v;
}

// branchless stable sorted insert (ascending by d; ties keep existing = earlier j)
__device__ __forceinline__ void sorted_insert(float (&bd)[KK], int (&bi)[KK],
                                              float d, int j) {
    bool c[KK];
#pragma unroll
    for (int t = 0; t < KK; ++t) c[t] = d < bd[t];
#pragma unroll
    for (int t = KK - 1; t >= 1; --t) {
        bd[t] = c[t] ? (c[t - 1] ? bd[t - 1] : d) : bd[t];
        bi[t] = c[t] ? (c[t - 1] ? bi[t - 1] : j) : bi[t];
    }
    bd[0] = c[0] ? d : bd[0];
    bi[0] = c[0] ? j : bi[0];
}

// Exact top-16 nearest of node i among NN candidates (self excluded).
// bd/bi sorted ascending, registers only. pend: per-lane LDS columns.
__device__ __forceinline__ void knn_scan(const float4* __restrict__ posq,
                                         float* __restrict__ pend_d,
                                         u16* __restrict__ pend_j,
                                         int tid, int i,
                                         u16* __restrict__ idx_out) {
    const float4 meq = posq[i];
    const float mex = -2.0f * meq.x, mey = -2.0f * meq.y, mez = -2.0f * meq.z;
    const float mew = meq.w;
    float bd[KK];
    int bi[KK];
#pragma unroll
    for (int t = 0; t < KK; ++t) { bd[t] = FINF; bi[t] = 0; }
    float T = FINF;
    int cnt = 0;

    for (int j0 = 0; j0 < NN; j0 += 8) {
        float4 p[8];
#pragma unroll
        for (int u = 0; u < 8; ++u) p[u] = posq[j0 + u];
#pragma unroll
        for (int u = 0; u < 8; ++u) {
            const int j = j0 + u;
            float d2 = fmaf(mex, p[u].x, fmaf(mey, p[u].y,
                          fmaf(mez, p[u].z, mew + p[u].w)));
            bool pass = (d2 < T) && (j != i);
            if (pass) {
                pend_d[tid + 256 * cnt] = d2;
                pend_j[tid + 256 * cnt] = (u16)j;
                ++cnt;
            }
        }
        if (__any(cnt >= PCAP)) {
#pragma unroll 1
            for (int s = 0; s < PMAX; ++s) {
                float d = (s < cnt) ? pend_d[tid + 256 * s] : FINF;
                int j = pend_j[tid + 256 * s];
                if (__any(d < bd[KK - 1])) sorted_insert(bd, bi, d, j);
            }
            cnt = 0;
            T = bd[KK - 1];
        }
    }
#pragma unroll 1
    for (int s = 0; s < PCAP; ++s) {   // final flush: all lanes have cnt <= 15
        float d = (s < cnt) ? pend_d[tid + 256 * s] : FINF;
        int j = pend_j[tid + 256 * s];
        if (__any(d < bd[KK - 1])) sorted_insert(bd, bi, d, j);
    }
#pragma unroll
    for (int t = 0; t < KK; ++t) idx_out[t] = (u16)bi[t];
}

// ---------------- kNN on xyz -> idx ------------------------------------------------
__global__ __launch_bounds__(256) void knn1(
    const float* __restrict__ x,    // [NG*NN*3]
    u16* __restrict__ idx)          // [NG*NN*16]
{
    __shared__ float4 posq[NN];              // 16 KB
    __shared__ float pend_d[256 * PMAX];     // 23 KB
    __shared__ u16 pend_j[256 * PMAX];       // 11.5 KB

    const int g = blockIdx.x >> 2;
    const int chunk = blockIdx.x & 3;
    const int tid = threadIdx.x;

    for (int n = tid; n < NN; n += 256) {
        const float* xp = x + (size_t)(g * NN + n) * 3;
        float px = xp[0], py = xp[1], pz = xp[2];
        posq[n] = make_float4(px, py, pz, px * px + py * py + pz * pz);
    }
    __syncthreads();

    const int i = chunk * 256 + tid;
    knn_scan(posq, pend_d, pend_j, tid, i, idx + (size_t)(g * NN + i) * KK);
}

// ---------------- kNN on h1[:, :3] -> idx ------------------------------------------
__global__ __launch_bounds__(256) void knn2(
    const float* __restrict__ h1,   // [NG*NN*16]
    u16* __restrict__ idx)          // [NG*NN*16]
{
    __shared__ float4 posq[NN];
    __shared__ float pend_d[256 * PMAX];
    __shared__ u16 pend_j[256 * PMAX];

    const int g = blockIdx.x >> 2;
    const int chunk = blockIdx.x & 3;
    const int tid = threadIdx.x;

    for (int n = tid; n < NN; n += 256) {
        const float4 a = *(const float4*)(h1 + (size_t)(g * NN + n) * 16);
        posq[n] = make_float4(a.x, a.y, a.z, a.x * a.x + a.y * a.y + a.z * a.z);
    }
    __syncthreads();

    const int i = chunk * 256 + tid;
    knn_scan(posq, pend_d, pend_j, tid, i, idx + (size_t)(g * NN + i) * KK);
}

// ---------------- EdgeConv 1: [6->16->16], sum over k ------------------------------
__global__ __launch_bounds__(256) void conv1(
    const float* __restrict__ x,    // [NG*NN*3]
    const u16* __restrict__ idx,    // [NG*NN*16]
    const float* __restrict__ W1,   // [6*16]
    const float* __restrict__ b1,   // [16]
    const float* __restrict__ W2,   // [16*16]
    const float* __restrict__ b2,   // [16]
    float* __restrict__ h1)         // [NG*NN*16]
{
    __shared__ float4 posq[NN];
    __shared__ float w1[6 * 16];
    __shared__ float w2[16 * 16];
    __shared__ float bb1[16], bb2[16];

    const int g = blockIdx.x >> 2;
    const int chunk = blockIdx.x & 3;
    const int tid = threadIdx.x;

    if (tid < 96) w1[tid] = W1[tid];
    w2[tid] = W2[tid];
    if (tid < 16) { bb1[tid] = b1[tid]; bb2[tid] = b2[tid]; }

    for (int n = tid; n < NN; n += 256) {
        const float* xp = x + (size_t)(g * NN + n) * 3;
        posq[n] = make_float4(xp[0], xp[1], xp[2], 0.0f);
    }
    __syncthreads();

    const int i = chunk * 256 + tid;
    const float4 me = posq[i];
    const u16* my_idx = idx + (size_t)(g * NN + i) * KK;

    // s1[o] = b1[o] + sum_f xi_f * (W1[f,o] - W1[3+f,o])
    float s1[16];
#pragma unroll
    for (int o = 0; o < 16; ++o) {
        s1[o] = bb1[o]
              + me.x * (w1[0 * 16 + o] - w1[3 * 16 + o])
              + me.y * (w1[1 * 16 + o] - w1[4 * 16 + o])
              + me.z * (w1[2 * 16 + o] - w1[5 * 16 + o]);
    }

    float acc[16];
#pragma unroll
    for (int o = 0; o < 16; ++o) acc[o] = 0.0f;

#pragma unroll 1
    for (int t = 0; t < KK; ++t) {
        const int j = my_idx[t];
        float4 pj = posq[j];
        float m1[16];
#pragma unroll
        for (int o = 0; o < 16; ++o) {
            float v = s1[o];
            v += pj.x * w1[3 * 16 + o];
            v += pj.y * w1[4 * 16 + o];
            v += pj.z * w1[5 * 16 + o];
            m1[o] = leaky(v);
        }
#pragma unroll
        for (int o = 0; o < 16; ++o) {
            float v = bb2[o];
#pragma unroll
            for (int f = 0; f < 16; ++f) v += m1[f] * w2[f * 16 + o];
            acc[o] += leaky(v);
        }
    }

    float4* out = (float4*)(h1 + (size_t)(g * NN + i) * 16);
    out[0] = make_float4(acc[0], acc[1], acc[2], acc[3]);
    out[1] = make_float4(acc[4], acc[5], acc[6], acc[7]);
    out[2] = make_float4(acc[8], acc[9], acc[10], acc[11]);
    out[3] = make_float4(acc[12], acc[13], acc[14], acc[15]);
}

// ---------- EdgeConv 2 [32->16->16] + post-MLP [35->16->16] + block-partial pool ----
// h1 tile staged in LDS (kills gather amplification). NO min-waves bound: the
// kernel needs ~160+ VGPRs; capping at 128 (round 5) spilled 2.3 GB to scratch.
__global__ __launch_bounds__(256) void conv2_post(
    const float* __restrict__ x,    // [NG*NN*3]
    const float* __restrict__ h1,   // [NG*NN*16]
    const u16* __restrict__ idx,    // [NG*NN*16]
    const float* __restrict__ W1,   // [32*16]
    const float* __restrict__ b1,   // [16]
    const float* __restrict__ W2,   // [16*16]
    const float* __restrict__ b2,   // [16]
    const float* __restrict__ Wp1, const float* __restrict__ bp1,   // [35*16],[16]
    const float* __restrict__ Wp2, const float* __restrict__ bp2,   // [16*16],[16]
    float* __restrict__ partial)    // [512*48]  (per-block: min16,max16,sum16)
{
    __shared__ float4 tile4[NN * 4];        // 64 KB: full h1 tile of this graph
    __shared__ float w1hi[16 * 16];         // W1[16+f, o]
    __shared__ float wd[16 * 16];           // W1[f,o] - W1[16+f,o]
    __shared__ float w2[16 * 16];
    __shared__ float wp1[35 * 16];
    __shared__ float wp2[16 * 16];
    __shared__ float bb1[16], bb2[16], sbp1[16], sbp2[16];
    __shared__ float red[3][4][16];

    const int g = blockIdx.x >> 2;
    const int chunk = blockIdx.x & 3;
    const int tid = threadIdx.x;

    wd[tid]   = W1[tid] - W1[256 + tid];
    w1hi[tid] = W1[256 + tid];
    w2[tid] = W2[tid];
    wp2[tid] = Wp2[tid];
    for (int t = tid; t < 560; t += 256) wp1[t] = Wp1[t];
    if (tid < 16) {
        bb1[tid] = b1[tid]; bb2[tid] = b2[tid];
        sbp1[tid] = bp1[tid]; sbp2[tid] = bp2[tid];
    }

    const float4* src4 = (const float4*)(h1 + (size_t)g * NN * 16);
    for (int t = tid; t < NN * 4; t += 256) tile4[t] = src4[t];
    __syncthreads();

    const int i = chunk * 256 + tid;
    const u16* my_idx = idx + (size_t)(g * NN + i) * KK;

    // own features from LDS
    float4 a0 = tile4[i * 4 + 0], a1 = tile4[i * 4 + 1];
    float4 a2 = tile4[i * 4 + 2], a3 = tile4[i * 4 + 3];

    // s1[o] = b1[o] + sum_f xi_f * wd[f,o]
    float s1[16];
#pragma unroll
    for (int o = 0; o < 16; ++o) {
        float v = bb1[o];
        v += a0.x * wd[0 * 16 + o];  v += a0.y * wd[1 * 16 + o];
        v += a0.z * wd[2 * 16 + o];  v += a0.w * wd[3 * 16 + o];
        v += a1.x * wd[4 * 16 + o];  v += a1.y * wd[5 * 16 + o];
        v += a1.z * wd[6 * 16 + o];  v += a1.w * wd[7 * 16 + o];
        v += a2.x * wd[8 * 16 + o];  v += a2.y * wd[9 * 16 + o];
        v += a2.z * wd[10 * 16 + o]; v += a2.w * wd[11 * 16 + o];
        v += a3.x * wd[12 * 16 + o]; v += a3.y * wd[13 * 16 + o];
        v += a3.z * wd[14 * 16 + o]; v += a3.w * wd[15 * 16 + o];
        s1[o] = v;
    }

    float acc[16];
#pragma unroll
    for (int o = 0; o < 16; ++o) acc[o] = 0.0f;

#pragma unroll 1
    for (int t = 0; t < KK; ++t) {
        const int j = my_idx[t];
        float4 j0 = tile4[j * 4 + 0], j1 = tile4[j * 4 + 1];
        float4 j2 = tile4[j * 4 + 2], j3 = tile4[j * 4 + 3];
        float m1[16];
#pragma unroll
        for (int o = 0; o < 16; ++o) {
            float v = s1[o];
            v += j0.x * w1hi[0 * 16 + o];  v += j0.y * w1hi[1 * 16 + o];
            v += j0.z * w1hi[2 * 16 + o];  v += j0.w * w1hi[3 * 16 + o];
            v += j1.x * w1hi[4 * 16 + o];  v += j1.y * w1hi[5 * 16 + o];
            v += j1.z * w1hi[6 * 16 + o];  v += j1.w * w1hi[7 * 16 + o];
            v += j2.x * w1hi[8 * 16 + o];  v += j2.y * w1hi[9 * 16 + o];
            v += j2.z * w1hi[10 * 16 + o]; v += j2.w * w1hi[11 * 16 + o];
            v += j3.x * w1hi[12 * 16 + o]; v += j3.y * w1hi[13 * 16 + o];
            v += j3.z * w1hi[14 * 16 + o]; v += j3.w * w1hi[15 * 16 + o];
            m1[o] = leaky(v);
        }
#pragma unroll
        for (int o = 0; o < 16; ++o) {
            float v = bb2[o];
#pragma unroll
            for (int f = 0; f < 16; ++f) v += m1[f] * w2[f * 16 + o];
            acc[o] += leaky(v);
        }
    }

    // post-MLP: p1 = leaky(bp1 + x*Wp1[0:3] + xi*Wp1[3:19] + acc*Wp1[19:35])
    const float* xp = x + (size_t)(g * NN + i) * 3;
    const float x0 = xp[0], x1 = xp[1], x2 = xp[2];
    float p1[16];
#pragma unroll
    for (int o = 0; o < 16; ++o) {
        float v = sbp1[o];
        v += x0 * wp1[0 * 16 + o];
        v += x1 * wp1[1 * 16 + o];
        v += x2 * wp1[2 * 16 + o];
        v += a0.x * wp1[3 * 16 + o];   v += a0.y * wp1[4 * 16 + o];
        v += a0.z * wp1[5 * 16 + o];   v += a0.w * wp1[6 * 16 + o];
        v += a1.x * wp1[7 * 16 + o];   v += a1.y * wp1[8 * 16 + o];
        v += a1.z * wp1[9 * 16 + o];   v += a1.w * wp1[10 * 16 + o];
        v += a2.x * wp1[11 * 16 + o];  v += a2.y * wp1[12 * 16 + o];
        v += a2.z * wp1[13 * 16 + o];  v += a2.w * wp1[14 * 16 + o];
        v += a3.x * wp1[15 * 16 + o];  v += a3.y * wp1[16 * 16 + o];
        v += a3.z * wp1[17 * 16 + o];  v += a3.w * wp1[18 * 16 + o];
#pragma unroll
        for (int f = 0; f < 16; ++f) v += acc[f] * wp1[(19 + f) * 16 + o];
        p1[o] = leaky(v);
    }

    float mn[16], mx[16], sm[16];
#pragma unroll
    for (int o = 0; o < 16; ++o) {
        float v = sbp2[o];
#pragma unroll
        for (int f = 0; f < 16; ++f) v += p1[f] * wp2[f * 16 + o];
        float p2 = leaky(v);
        mn[o] = p2; mx[o] = p2; sm[o] = p2;
    }

#pragma unroll
    for (int off = 32; off >= 1; off >>= 1) {
#pragma unroll
        for (int o = 0; o < 16; ++o) {
            mn[o] = fminf(mn[o], __shfl_xor(mn[o], off));
            mx[o] = fmaxf(mx[o], __shfl_xor(mx[o], off));
            sm[o] += __shfl_xor(sm[o], off);
        }
    }
    const int wave = tid >> 6;
    const int lane = tid & 63;
    if (lane == 0) {
#pragma unroll
        for (int o = 0; o < 16; ++o) {
            red[0][wave][o] = mn[o];
            red[1][wave][o] = mx[o];
            red[2][wave][o] = sm[o];
        }
    }
    __syncthreads();

    if (tid < 48) {
        const int stat = tid >> 4, o = tid & 15;
        float v;
        if (stat == 0)
            v = fminf(fminf(red[0][0][o], red[0][1][o]), fminf(red[0][2][o], red[0][3][o]));
        else if (stat == 1)
            v = fmaxf(fmaxf(red[1][0][o], red[1][1][o]), fmaxf(red[1][2][o], red[1][3][o]));
        else
            v = red[2][0][o] + red[2][1][o] + red[2][2][o] + red[2][3][o];
        partial[blockIdx.x * 48 + tid] = v;
    }
}

// -------- Finalize: combine 4 block-partials per graph + readout [48->128->10] -----
__global__ __launch_bounds__(128) void finalize(
    const float* __restrict__ partial,   // [512*48]
    const float* __restrict__ Wr1, const float* __restrict__ br1,   // [48*128],[128]
    const float* __restrict__ Wr2, const float* __restrict__ br2,   // [128*10],[10]
    float* __restrict__ out)             // [NG*10]
{
    __shared__ float pooled[48];
    __shared__ float hidden[128];

    const int g = blockIdx.x;
    const int tid = threadIdx.x;

    if (tid < 48) {
        const int stat = tid >> 4;
        float a = partial[(g * 4 + 0) * 48 + tid];
        float b = partial[(g * 4 + 1) * 48 + tid];
        float c = partial[(g * 4 + 2) * 48 + tid];
        float d = partial[(g * 4 + 3) * 48 + tid];
        float v;
        if (stat == 0)      v = fminf(fminf(a, b), fminf(c, d));
        else if (stat == 1) v = fmaxf(fmaxf(a, b), fmaxf(c, d));
        else                v = (a + b + c + d) * (1.0f / NN);
        pooled[tid] = v;
    }
    __syncthreads();

    {
        float v = br1[tid];
#pragma unroll
        for (int f = 0; f < 48; ++f) v += pooled[f] * Wr1[f * 128 + tid];
        hidden[tid] = leaky(v);
    }
    __syncthreads();

    if (tid < 10) {
        float v = br2[tid];
#pragma unroll
        for (int f = 0; f < 128; ++f) v += hidden[f] * Wr2[f * 10 + tid];
        out[g * 10 + tid] = v;
    }
}

extern "C" void kernel_launch(void* const* d_in, const int* in_sizes, int n_in,
                              void* d_out, int out_size, void* d_ws, size_t ws_size,
                              hipStream_t stream) {
    const float* x   = (const float*)d_in[0];
    const float* W1a = (const float*)d_in[2];
    const float* b1a = (const float*)d_in[3];
    const float* W2a = (const float*)d_in[4];
    const float* b2a = (const float*)d_in[5];
    const float* W1b = (const float*)d_in[6];
    const float* b1b = (const float*)d_in[7];
    const float* W2b = (const float*)d_in[8];
    const float* b2b = (const float*)d_in[9];
    const float* Wp1 = (const float*)d_in[10];
    const float* bp1 = (const float*)d_in[11];
    const float* Wp2 = (const float*)d_in[12];
    const float* bp2 = (const float*)d_in[13];
    const float* Wr1 = (const float*)d_in[14];
    const float* br1 = (const float*)d_in[15];
    const float* Wr2 = (const float*)d_in[16];
    const float* br2 = (const float*)d_in[17];
    float* out = (float*)d_out;

    float* h1 = (float*)d_ws;                         // 8 MB
    u16* idx = (u16*)(h1 + (size_t)NG * NN * 16);     // 4 MB (reused by both kNNs)
    float* partial = (float*)(idx + (size_t)NG * NN * KK);  // 512*48 floats

    knn1<<<NG * 4, 256, 0, stream>>>(x, idx);
    conv1<<<NG * 4, 256, 0, stream>>>(x, idx, W1a, b1a, W2a, b2a, h1);
    knn2<<<NG * 4, 256, 0, stream>>>(h1, idx);
    conv2_post<<<NG * 4, 256, 0, stream>>>(x, h1, idx, W1b, b1b, W2b, b2b,
                                           Wp1, bp1, Wp2, bp2, partial);
    finalize<<<NG, 128, 0, stream>>>(partial, Wr1, br1, Wr2, br2, out);
}

// Round 8
// 764.235 us; speedup vs baseline: 1.8104x; 1.2864x over previous
//
#include <hip/hip_runtime.h>

#define NG 128
#define NN 1024
#define KK 16
#define PCAP 16           // flush trigger (checked once per 8-candidate group)
#define PMAX 23           // max pending per lane (15 carry + 8 new)
#define SLOPE 0.01f
#define FINF 3.0e38f

typedef unsigned short u16;

__device__ __forceinline__ float leaky(float v) {
    return v >= 0.0f ? v : SLOPE * v;
}

// branchless stable sorted insert (ascending by d; ties keep existing = earlier j)
__device__ __forceinline__ void sorted_insert(float (&bd)[KK], int (&bi)[KK],
                                              float d, int j) {
    bool c[KK];
#pragma unroll
    for (int t = 0; t < KK; ++t) c[t] = d < bd[t];
#pragma unroll
    for (int t = KK - 1; t >= 1; --t) {
        bd[t] = c[t] ? (c[t - 1] ? bd[t - 1] : d) : bd[t];
        bi[t] = c[t] ? (c[t - 1] ? bi[t - 1] : j) : bi[t];
    }
    bd[0] = c[0] ? d : bd[0];
    bi[0] = c[0] ? j : bi[0];
}

// Exact top-16 nearest of node i among NN candidates (self excluded).
// bd/bi sorted ascending, registers only. pend: per-lane LDS columns.
__device__ __forceinline__ void knn_scan(const float4* __restrict__ posq,
                                         float* __restrict__ pend_d,
                                         u16* __restrict__ pend_j,
                                         int tid, int i,
                                         u16* __restrict__ idx_out) {
    const float4 meq = posq[i];
    const float mex = -2.0f * meq.x, mey = -2.0f * meq.y, mez = -2.0f * meq.z;
    const float mew = meq.w;
    float bd[KK];
    int bi[KK];
#pragma unroll
    for (int t = 0; t < KK; ++t) { bd[t] = FINF; bi[t] = 0; }
    float T = FINF;
    int cnt = 0;

    for (int j0 = 0; j0 < NN; j0 += 8) {
        float4 p[8];
#pragma unroll
        for (int u = 0; u < 8; ++u) p[u] = posq[j0 + u];
#pragma unroll
        for (int u = 0; u < 8; ++u) {
            const int j = j0 + u;
            float d2 = fmaf(mex, p[u].x, fmaf(mey, p[u].y,
                          fmaf(mez, p[u].z, mew + p[u].w)));
            bool pass = (d2 < T) && (j != i);
            if (pass) {
                pend_d[tid + 256 * cnt] = d2;
                pend_j[tid + 256 * cnt] = (u16)j;
                ++cnt;
            }
        }
        if (__any(cnt >= PCAP)) {
#pragma unroll 1
            for (int s = 0; s < PMAX; ++s) {
                float d = (s < cnt) ? pend_d[tid + 256 * s] : FINF;
                int j = pend_j[tid + 256 * s];
                if (__any(d < bd[KK - 1])) sorted_insert(bd, bi, d, j);
            }
            cnt = 0;
            T = bd[KK - 1];
        }
    }
#pragma unroll 1
    for (int s = 0; s < PCAP; ++s) {   // final flush: all lanes have cnt <= 15
        float d = (s < cnt) ? pend_d[tid + 256 * s] : FINF;
        int j = pend_j[tid + 256 * s];
        if (__any(d < bd[KK - 1])) sorted_insert(bd, bi, d, j);
    }
#pragma unroll
    for (int t = 0; t < KK; ++t) idx_out[t] = (u16)bi[t];
}

// ---------------- kNN on xyz -> idx ------------------------------------------------
__global__ __launch_bounds__(256) void knn1(
    const float* __restrict__ x,    // [NG*NN*3]
    u16* __restrict__ idx)          // [NG*NN*16]
{
    __shared__ float4 posq[NN];              // 16 KB
    __shared__ float pend_d[256 * PMAX];     // 23 KB
    __shared__ u16 pend_j[256 * PMAX];       // 11.5 KB

    const int g = blockIdx.x >> 2;
    const int chunk = blockIdx.x & 3;
    const int tid = threadIdx.x;

    for (int n = tid; n < NN; n += 256) {
        const float* xp = x + (size_t)(g * NN + n) * 3;
        float px = xp[0], py = xp[1], pz = xp[2];
        posq[n] = make_float4(px, py, pz, px * px + py * py + pz * pz);
    }
    __syncthreads();

    const int i = chunk * 256 + tid;
    knn_scan(posq, pend_d, pend_j, tid, i, idx + (size_t)(g * NN + i) * KK);
}

// ---------------- kNN on h1[:, :3] -> idx ------------------------------------------
__global__ __launch_bounds__(256) void knn2(
    const float* __restrict__ h1,   // [NG*NN*16]
    u16* __restrict__ idx)          // [NG*NN*16]
{
    __shared__ float4 posq[NN];
    __shared__ float pend_d[256 * PMAX];
    __shared__ u16 pend_j[256 * PMAX];

    const int g = blockIdx.x >> 2;
    const int chunk = blockIdx.x & 3;
    const int tid = threadIdx.x;

    for (int n = tid; n < NN; n += 256) {
        const float4 a = *(const float4*)(h1 + (size_t)(g * NN + n) * 16);
        posq[n] = make_float4(a.x, a.y, a.z, a.x * a.x + a.y * a.y + a.z * a.z);
    }
    __syncthreads();

    const int i = chunk * 256 + tid;
    knn_scan(posq, pend_d, pend_j, tid, i, idx + (size_t)(g * NN + i) * KK);
}

// ---------------- EdgeConv 1: [6->16->16], sum over k ------------------------------
__global__ __launch_bounds__(256) void conv1(
    const float* __restrict__ x,    // [NG*NN*3]
    const u16* __restrict__ idx,    // [NG*NN*16]
    const float* __restrict__ W1,   // [6*16]
    const float* __restrict__ b1,   // [16]
    const float* __restrict__ W2,   // [16*16]
    const float* __restrict__ b2,   // [16]
    float* __restrict__ h1)         // [NG*NN*16]
{
    __shared__ float4 posq[NN];
    __shared__ float w1[6 * 16];
    __shared__ float w2[16 * 16];
    __shared__ float bb1[16], bb2[16];

    const int g = blockIdx.x >> 2;
    const int chunk = blockIdx.x & 3;
    const int tid = threadIdx.x;

    if (tid < 96) w1[tid] = W1[tid];
    w2[tid] = W2[tid];
    if (tid < 16) { bb1[tid] = b1[tid]; bb2[tid] = b2[tid]; }

    for (int n = tid; n < NN; n += 256) {
        const float* xp = x + (size_t)(g * NN + n) * 3;
        posq[n] = make_float4(xp[0], xp[1], xp[2], 0.0f);
    }
    __syncthreads();

    const int i = chunk * 256 + tid;
    const float4 me = posq[i];
    const u16* my_idx = idx + (size_t)(g * NN + i) * KK;

    // s1[o] = b1[o] + sum_f xi_f * (W1[f,o] - W1[3+f,o])
    float s1[16];
#pragma unroll
    for (int o = 0; o < 16; ++o) {
        s1[o] = bb1[o]
              + me.x * (w1[0 * 16 + o] - w1[3 * 16 + o])
              + me.y * (w1[1 * 16 + o] - w1[4 * 16 + o])
              + me.z * (w1[2 * 16 + o] - w1[5 * 16 + o]);
    }

    float acc[16];
#pragma unroll
    for (int o = 0; o < 16; ++o) acc[o] = 0.0f;

#pragma unroll 1
    for (int t = 0; t < KK; ++t) {
        const int j = my_idx[t];
        float4 pj = posq[j];
        float m1[16];
#pragma unroll
        for (int o = 0; o < 16; ++o) {
            float v = s1[o];
            v += pj.x * w1[3 * 16 + o];
            v += pj.y * w1[4 * 16 + o];
            v += pj.z * w1[5 * 16 + o];
            m1[o] = leaky(v);
        }
#pragma unroll
        for (int o = 0; o < 16; ++o) {
            float v = bb2[o];
#pragma unroll
            for (int f = 0; f < 16; ++f) v += m1[f] * w2[f * 16 + o];
            acc[o] += leaky(v);
        }
    }

    float4* out = (float4*)(h1 + (size_t)(g * NN + i) * 16);
    out[0] = make_float4(acc[0], acc[1], acc[2], acc[3]);
    out[1] = make_float4(acc[4], acc[5], acc[6], acc[7]);
    out[2] = make_float4(acc[8], acc[9], acc[10], acc[11]);
    out[3] = make_float4(acc[12], acc[13], acc[14], acc[15]);
}

// ---------------- EdgeConv 2: [32->16->16], sum over k (LDS h1 tile) ---------------
// Standalone: a0..a3 die after s1, loop live-set ~80 VGPR -> no spill.
__global__ __launch_bounds__(256) void conv2(
    const float* __restrict__ h1,   // [NG*NN*16]
    const u16* __restrict__ idx,    // [NG*NN*16]
    const float* __restrict__ W1,   // [32*16]
    const float* __restrict__ b1,   // [16]
    const float* __restrict__ W2,   // [16*16]
    const float* __restrict__ b2,   // [16]
    float* __restrict__ h2)         // [NG*NN*16]
{
    __shared__ float4 tile4[NN * 4];        // 64 KB: full h1 tile of this graph
    __shared__ float w1hi[16 * 16];         // W1[16+f, o]
    __shared__ float wd[16 * 16];           // W1[f,o] - W1[16+f,o]
    __shared__ float w2s[16 * 16];
    __shared__ float bb1[16], bb2[16];

    const int g = blockIdx.x >> 2;
    const int chunk = blockIdx.x & 3;
    const int tid = threadIdx.x;

    wd[tid]   = W1[tid] - W1[256 + tid];
    w1hi[tid] = W1[256 + tid];
    w2s[tid] = W2[tid];
    if (tid < 16) { bb1[tid] = b1[tid]; bb2[tid] = b2[tid]; }

    const float4* src4 = (const float4*)(h1 + (size_t)g * NN * 16);
    for (int t = tid; t < NN * 4; t += 256) tile4[t] = src4[t];
    __syncthreads();

    const int i = chunk * 256 + tid;
    const u16* my_idx = idx + (size_t)(g * NN + i) * KK;

    // s1[o] = b1[o] + sum_f xi_f * wd[f,o]   (a0..a3 dead afterwards)
    float s1[16];
    {
        float4 a0 = tile4[i * 4 + 0], a1 = tile4[i * 4 + 1];
        float4 a2 = tile4[i * 4 + 2], a3 = tile4[i * 4 + 3];
#pragma unroll
        for (int o = 0; o < 16; ++o) {
            float v = bb1[o];
            v += a0.x * wd[0 * 16 + o];  v += a0.y * wd[1 * 16 + o];
            v += a0.z * wd[2 * 16 + o];  v += a0.w * wd[3 * 16 + o];
            v += a1.x * wd[4 * 16 + o];  v += a1.y * wd[5 * 16 + o];
            v += a1.z * wd[6 * 16 + o];  v += a1.w * wd[7 * 16 + o];
            v += a2.x * wd[8 * 16 + o];  v += a2.y * wd[9 * 16 + o];
            v += a2.z * wd[10 * 16 + o]; v += a2.w * wd[11 * 16 + o];
            v += a3.x * wd[12 * 16 + o]; v += a3.y * wd[13 * 16 + o];
            v += a3.z * wd[14 * 16 + o]; v += a3.w * wd[15 * 16 + o];
            s1[o] = v;
        }
    }

    float acc[16];
#pragma unroll
    for (int o = 0; o < 16; ++o) acc[o] = 0.0f;

#pragma unroll 1
    for (int t = 0; t < KK; ++t) {
        const int j = my_idx[t];
        float4 j0 = tile4[j * 4 + 0], j1 = tile4[j * 4 + 1];
        float4 j2 = tile4[j * 4 + 2], j3 = tile4[j * 4 + 3];
        float m1[16];
#pragma unroll
        for (int o = 0; o < 16; ++o) {
            float v = s1[o];
            v += j0.x * w1hi[0 * 16 + o];  v += j0.y * w1hi[1 * 16 + o];
            v += j0.z * w1hi[2 * 16 + o];  v += j0.w * w1hi[3 * 16 + o];
            v += j1.x * w1hi[4 * 16 + o];  v += j1.y * w1hi[5 * 16 + o];
            v += j1.z * w1hi[6 * 16 + o];  v += j1.w * w1hi[7 * 16 + o];
            v += j2.x * w1hi[8 * 16 + o];  v += j2.y * w1hi[9 * 16 + o];
            v += j2.z * w1hi[10 * 16 + o]; v += j2.w * w1hi[11 * 16 + o];
            v += j3.x * w1hi[12 * 16 + o]; v += j3.y * w1hi[13 * 16 + o];
            v += j3.z * w1hi[14 * 16 + o]; v += j3.w * w1hi[15 * 16 + o];
            m1[o] = leaky(v);
        }
#pragma unroll
        for (int o = 0; o < 16; ++o) {
            float v = bb2[o];
#pragma unroll
            for (int f = 0; f < 16; ++f) v += m1[f] * w2s[f * 16 + o];
            acc[o] += leaky(v);
        }
    }

    float4* out = (float4*)(h2 + (size_t)(g * NN + i) * 16);
    out[0] = make_float4(acc[0], acc[1], acc[2], acc[3]);
    out[1] = make_float4(acc[4], acc[5], acc[6], acc[7]);
    out[2] = make_float4(acc[8], acc[9], acc[10], acc[11]);
    out[3] = make_float4(acc[12], acc[13], acc[14], acc[15]);
}

// ---------- Post-MLP [35->16->16] + block-partial pooling --------------------------
__global__ __launch_bounds__(256) void post_pool(
    const float* __restrict__ x,    // [NG*NN*3]
    const float* __restrict__ h1,   // [NG*NN*16]
    const float* __restrict__ h2,   // [NG*NN*16]
    const float* __restrict__ Wp1, const float* __restrict__ bp1,   // [35*16],[16]
    const float* __restrict__ Wp2, const float* __restrict__ bp2,   // [16*16],[16]
    float* __restrict__ partial)    // [512*48]  (per-block: min16,max16,sum16)
{
    __shared__ float wp1[35 * 16];
    __shared__ float wp2[16 * 16];
    __shared__ float sbp1[16], sbp2[16];
    __shared__ float red[3][4][16];

    const int g = blockIdx.x >> 2;
    const int chunk = blockIdx.x & 3;
    const int tid = threadIdx.x;

    wp2[tid] = Wp2[tid];
    for (int t = tid; t < 560; t += 256) wp1[t] = Wp1[t];
    if (tid < 16) { sbp1[tid] = bp1[tid]; sbp2[tid] = bp2[tid]; }
    __syncthreads();

    const int i = chunk * 256 + tid;
    const float* xp = x + (size_t)(g * NN + i) * 3;
    const float x0 = xp[0], x1 = xp[1], x2 = xp[2];
    const float4* p1v = (const float4*)(h1 + (size_t)(g * NN + i) * 16);
    float4 a0 = p1v[0], a1 = p1v[1], a2 = p1v[2], a3 = p1v[3];
    const float4* p2v = (const float4*)(h2 + (size_t)(g * NN + i) * 16);
    float4 c0 = p2v[0], c1 = p2v[1], c2 = p2v[2], c3 = p2v[3];

    float p1[16];
#pragma unroll
    for (int o = 0; o < 16; ++o) {
        float v = sbp1[o];
        v += x0 * wp1[0 * 16 + o];
        v += x1 * wp1[1 * 16 + o];
        v += x2 * wp1[2 * 16 + o];
        v += a0.x * wp1[3 * 16 + o];   v += a0.y * wp1[4 * 16 + o];
        v += a0.z * wp1[5 * 16 + o];   v += a0.w * wp1[6 * 16 + o];
        v += a1.x * wp1[7 * 16 + o];   v += a1.y * wp1[8 * 16 + o];
        v += a1.z * wp1[9 * 16 + o];   v += a1.w * wp1[10 * 16 + o];
        v += a2.x * wp1[11 * 16 + o];  v += a2.y * wp1[12 * 16 + o];
        v += a2.z * wp1[13 * 16 + o];  v += a2.w * wp1[14 * 16 + o];
        v += a3.x * wp1[15 * 16 + o];  v += a3.y * wp1[16 * 16 + o];
        v += a3.z * wp1[17 * 16 + o];  v += a3.w * wp1[18 * 16 + o];
        v += c0.x * wp1[19 * 16 + o];  v += c0.y * wp1[20 * 16 + o];
        v += c0.z * wp1[21 * 16 + o];  v += c0.w * wp1[22 * 16 + o];
        v += c1.x * wp1[23 * 16 + o];  v += c1.y * wp1[24 * 16 + o];
        v += c1.z * wp1[25 * 16 + o];  v += c1.w * wp1[26 * 16 + o];
        v += c2.x * wp1[27 * 16 + o];  v += c2.y * wp1[28 * 16 + o];
        v += c2.z * wp1[29 * 16 + o];  v += c2.w * wp1[30 * 16 + o];
        v += c3.x * wp1[31 * 16 + o];  v += c3.y * wp1[32 * 16 + o];
        v += c3.z * wp1[33 * 16 + o];  v += c3.w * wp1[34 * 16 + o];
        p1[o] = leaky(v);
    }

    float mn[16], mx[16], sm[16];
#pragma unroll
    for (int o = 0; o < 16; ++o) {
        float v = sbp2[o];
#pragma unroll
        for (int f = 0; f < 16; ++f) v += p1[f] * wp2[f * 16 + o];
        float p2 = leaky(v);
        mn[o] = p2; mx[o] = p2; sm[o] = p2;
    }

#pragma unroll
    for (int off = 32; off >= 1; off >>= 1) {
#pragma unroll
        for (int o = 0; o < 16; ++o) {
            mn[o] = fminf(mn[o], __shfl_xor(mn[o], off));
            mx[o] = fmaxf(mx[o], __shfl_xor(mx[o], off));
            sm[o] += __shfl_xor(sm[o], off);
        }
    }
    const int wave = tid >> 6;
    const int lane = tid & 63;
    if (lane == 0) {
#pragma unroll
        for (int o = 0; o < 16; ++o) {
            red[0][wave][o] = mn[o];
            red[1][wave][o] = mx[o];
            red[2][wave][o] = sm[o];
        }
    }
    __syncthreads();

    if (tid < 48) {
        const int stat = tid >> 4, o = tid & 15;
        float v;
        if (stat == 0)
            v = fminf(fminf(red[0][0][o], red[0][1][o]), fminf(red[0][2][o], red[0][3][o]));
        else if (stat == 1)
            v = fmaxf(fmaxf(red[1][0][o], red[1][1][o]), fmaxf(red[1][2][o], red[1][3][o]));
        else
            v = red[2][0][o] + red[2][1][o] + red[2][2][o] + red[2][3][o];
        partial[blockIdx.x * 48 + tid] = v;
    }
}

// -------- Finalize: combine 4 block-partials per graph + readout [48->128->10] -----
__global__ __launch_bounds__(128) void finalize(
    const float* __restrict__ partial,   // [512*48]
    const float* __restrict__ Wr1, const float* __restrict__ br1,   // [48*128],[128]
    const float* __restrict__ Wr2, const float* __restrict__ br2,   // [128*10],[10]
    float* __restrict__ out)             // [NG*10]
{
    __shared__ float pooled[48];
    __shared__ float hidden[128];

    const int g = blockIdx.x;
    const int tid = threadIdx.x;

    if (tid < 48) {
        const int stat = tid >> 4;
        float a = partial[(g * 4 + 0) * 48 + tid];
        float b = partial[(g * 4 + 1) * 48 + tid];
        float c = partial[(g * 4 + 2) * 48 + tid];
        float d = partial[(g * 4 + 3) * 48 + tid];
        float v;
        if (stat == 0)      v = fminf(fminf(a, b), fminf(c, d));
        else if (stat == 1) v = fmaxf(fmaxf(a, b), fmaxf(c, d));
        else                v = (a + b + c + d) * (1.0f / NN);
        pooled[tid] = v;
    }
    __syncthreads();

    {
        float v = br1[tid];
#pragma unroll
        for (int f = 0; f < 48; ++f) v += pooled[f] * Wr1[f * 128 + tid];
        hidden[tid] = leaky(v);
    }
    __syncthreads();

    if (tid < 10) {
        float v = br2[tid];
#pragma unroll
        for (int f = 0; f < 128; ++f) v += hidden[f] * Wr2[f * 10 + tid];
        out[g * 10 + tid] = v;
    }
}

extern "C" void kernel_launch(void* const* d_in, const int* in_sizes, int n_in,
                              void* d_out, int out_size, void* d_ws, size_t ws_size,
                              hipStream_t stream) {
    const float* x   = (const float*)d_in[0];
    const float* W1a = (const float*)d_in[2];
    const float* b1a = (const float*)d_in[3];
    const float* W2a = (const float*)d_in[4];
    const float* b2a = (const float*)d_in[5];
    const float* W1b = (const float*)d_in[6];
    const float* b1b = (const float*)d_in[7];
    const float* W2b = (const float*)d_in[8];
    const float* b2b = (const float*)d_in[9];
    const float* Wp1 = (const float*)d_in[10];
    const float* bp1 = (const float*)d_in[11];
    const float* Wp2 = (const float*)d_in[12];
    const float* bp2 = (const float*)d_in[13];
    const float* Wr1 = (const float*)d_in[14];
    const float* br1 = (const float*)d_in[15];
    const float* Wr2 = (const float*)d_in[16];
    const float* br2 = (const float*)d_in[17];
    float* out = (float*)d_out;

    float* h1 = (float*)d_ws;                         // 8 MB
    float* h2 = h1 + (size_t)NG * NN * 16;            // 8 MB
    u16* idx = (u16*)(h2 + (size_t)NG * NN * 16);     // 4 MB (reused by both kNNs)
    float* partial = (float*)(idx + (size_t)NG * NN * KK);  // 512*48 floats

    knn1<<<NG * 4, 256, 0, stream>>>(x, idx);
    conv1<<<NG * 4, 256, 0, stream>>>(x, idx, W1a, b1a, W2a, b2a, h1);
    knn2<<<NG * 4, 256, 0, stream>>>(h1, idx);
    conv2<<<NG * 4, 256, 0, stream>>>(h1, idx, W1b, b1b, W2b, b2b, h2);
    post_pool<<<NG * 4, 256, 0, stream>>>(x, h1, h2, Wp1, bp1, Wp2, bp2, partial);
    finalize<<<NG, 128, 0, stream>>>(partial, Wr1, br1, Wr2, br2, out);
}

// Round 9
// 550.122 us; speedup vs baseline: 2.5150x; 1.3892x over previous
//
#include <hip/hip_runtime.h>

#define NG 128
#define NN 1024
#define KK 16
#define PCAP 16           // flush trigger (checked once per 8-candidate group)
#define PMAX 23           // max pending per lane (15 carry + 8 new)
#define SLOPE 0.01f
#define FINF 3.0e38f

typedef unsigned short u16;

__device__ __forceinline__ float leaky(float v) {
    return v >= 0.0f ? v : SLOPE * v;
}

// branchless stable sorted insert (ascending by d; ties keep existing = earlier j)
__device__ __forceinline__ void sorted_insert(float (&bd)[KK], int (&bi)[KK],
                                              float d, int j) {
    bool c[KK];
#pragma unroll
    for (int t = 0; t < KK; ++t) c[t] = d < bd[t];
#pragma unroll
    for (int t = KK - 1; t >= 1; --t) {
        bd[t] = c[t] ? (c[t - 1] ? bd[t - 1] : d) : bd[t];
        bi[t] = c[t] ? (c[t - 1] ? bi[t - 1] : j) : bi[t];
    }
    bd[0] = c[0] ? d : bd[0];
    bi[0] = c[0] ? j : bi[0];
}

// Exact top-16 nearest of node i among NN candidates (self excluded).
__device__ __forceinline__ void knn_scan(const float4* __restrict__ posq,
                                         float* __restrict__ pend_d,
                                         u16* __restrict__ pend_j,
                                         int tid, int i,
                                         u16* __restrict__ idx_out) {
    const float4 meq = posq[i];
    const float mex = -2.0f * meq.x, mey = -2.0f * meq.y, mez = -2.0f * meq.z;
    const float mew = meq.w;
    float bd[KK];
    int bi[KK];
#pragma unroll
    for (int t = 0; t < KK; ++t) { bd[t] = FINF; bi[t] = 0; }
    float T = FINF;
    int cnt = 0;

    for (int j0 = 0; j0 < NN; j0 += 8) {
        float4 p[8];
#pragma unroll
        for (int u = 0; u < 8; ++u) p[u] = posq[j0 + u];
#pragma unroll
        for (int u = 0; u < 8; ++u) {
            const int j = j0 + u;
            float d2 = fmaf(mex, p[u].x, fmaf(mey, p[u].y,
                          fmaf(mez, p[u].z, mew + p[u].w)));
            bool pass = (d2 < T) && (j != i);
            if (pass) {
                pend_d[tid + 256 * cnt] = d2;
                pend_j[tid + 256 * cnt] = (u16)j;
                ++cnt;
            }
        }
        if (__any(cnt >= PCAP)) {
#pragma unroll 1
            for (int s = 0; s < PMAX; ++s) {
                float d = (s < cnt) ? pend_d[tid + 256 * s] : FINF;
                int j = pend_j[tid + 256 * s];
                if (__any(d < bd[KK - 1])) sorted_insert(bd, bi, d, j);
            }
            cnt = 0;
            T = bd[KK - 1];
        }
    }
#pragma unroll 1
    for (int s = 0; s < PCAP; ++s) {
        float d = (s < cnt) ? pend_d[tid + 256 * s] : FINF;
        int j = pend_j[tid + 256 * s];
        if (__any(d < bd[KK - 1])) sorted_insert(bd, bi, d, j);
    }
#pragma unroll
    for (int t = 0; t < KK; ++t) idx_out[t] = (u16)bi[t];
}

// ---------------- kNN on xyz -> idx ------------------------------------------------
__global__ __launch_bounds__(256) void knn1(
    const float* __restrict__ x, u16* __restrict__ idx)
{
    __shared__ float4 posq[NN];
    __shared__ float pend_d[256 * PMAX];
    __shared__ u16 pend_j[256 * PMAX];

    const int g = blockIdx.x >> 2;
    const int chunk = blockIdx.x & 3;
    const int tid = threadIdx.x;

    for (int n = tid; n < NN; n += 256) {
        const float* xp = x + (size_t)(g * NN + n) * 3;
        float px = xp[0], py = xp[1], pz = xp[2];
        posq[n] = make_float4(px, py, pz, px * px + py * py + pz * pz);
    }
    __syncthreads();

    const int i = chunk * 256 + tid;
    knn_scan(posq, pend_d, pend_j, tid, i, idx + (size_t)(g * NN + i) * KK);
}

// ---------------- kNN on h1[:, :3] -> idx ------------------------------------------
__global__ __launch_bounds__(256) void knn2(
    const float* __restrict__ h1, u16* __restrict__ idx)
{
    __shared__ float4 posq[NN];
    __shared__ float pend_d[256 * PMAX];
    __shared__ u16 pend_j[256 * PMAX];

    const int g = blockIdx.x >> 2;
    const int chunk = blockIdx.x & 3;
    const int tid = threadIdx.x;

    for (int n = tid; n < NN; n += 256) {
        const float4 a = *(const float4*)(h1 + (size_t)(g * NN + n) * 16);
        posq[n] = make_float4(a.x, a.y, a.z, a.x * a.x + a.y * a.y + a.z * a.z);
    }
    __syncthreads();

    const int i = chunk * 256 + tid;
    knn_scan(posq, pend_d, pend_j, tid, i, idx + (size_t)(g * NN + i) * KK);
}

// ---- shared edge pass: acc[o] = sum_t leaky(b2[o] + sum_f leaky(s1[f]+u_j[f]) * W2[f,o])
// Layer-2 weights live in a 128-float STATIC register array, one output-half at a
// time (unroll 1) -> live set ~200 VGPR, nothing for LICM to spill.
__device__ __forceinline__ void edge_pass(
    const float* __restrict__ u_lds,   // [NN*16] per-node layer-1 hi contributions
    const float (&s1)[16],
    const u16* __restrict__ my_idx,
    const float* __restrict__ W2,      // [16*16] global
    const float* __restrict__ b2,      // [16] global
    float* __restrict__ out_row)
{
#pragma unroll 1
    for (int half = 0; half < 2; ++half) {
        float4 w2h[16][2];
#pragma unroll
        for (int f = 0; f < 16; ++f) {
            w2h[f][0] = *(const float4*)(W2 + f * 16 + half * 8);
            w2h[f][1] = *(const float4*)(W2 + f * 16 + half * 8 + 4);
        }
        float bb[8];
#pragma unroll
        for (int oo = 0; oo < 8; ++oo) bb[oo] = b2[half * 8 + oo];

        float acc[8];
#pragma unroll
        for (int oo = 0; oo < 8; ++oo) acc[oo] = 0.0f;

#pragma unroll 1
        for (int t = 0; t < KK; ++t) {
            const int j = my_idx[t];
            const float4* uj4 = (const float4*)(u_lds + j * 16);
            float4 u0 = uj4[0], u1 = uj4[1], u2 = uj4[2], u3 = uj4[3];
            float m1[16];
            m1[0]  = leaky(s1[0]  + u0.x);  m1[1]  = leaky(s1[1]  + u0.y);
            m1[2]  = leaky(s1[2]  + u0.z);  m1[3]  = leaky(s1[3]  + u0.w);
            m1[4]  = leaky(s1[4]  + u1.x);  m1[5]  = leaky(s1[5]  + u1.y);
            m1[6]  = leaky(s1[6]  + u1.z);  m1[7]  = leaky(s1[7]  + u1.w);
            m1[8]  = leaky(s1[8]  + u2.x);  m1[9]  = leaky(s1[9]  + u2.y);
            m1[10] = leaky(s1[10] + u2.z);  m1[11] = leaky(s1[11] + u2.w);
            m1[12] = leaky(s1[12] + u3.x);  m1[13] = leaky(s1[13] + u3.y);
            m1[14] = leaky(s1[14] + u3.z);  m1[15] = leaky(s1[15] + u3.w);

            float v[8];
#pragma unroll
            for (int oo = 0; oo < 8; ++oo) v[oo] = bb[oo];
#pragma unroll
            for (int f = 0; f < 16; ++f) {
                float4 wa = w2h[f][0], wb = w2h[f][1];
                v[0] += m1[f] * wa.x;  v[1] += m1[f] * wa.y;
                v[2] += m1[f] * wa.z;  v[3] += m1[f] * wa.w;
                v[4] += m1[f] * wb.x;  v[5] += m1[f] * wb.y;
                v[6] += m1[f] * wb.z;  v[7] += m1[f] * wb.w;
            }
#pragma unroll
            for (int oo = 0; oo < 8; ++oo) acc[oo] += leaky(v[oo]);
        }
        float4* o4 = (float4*)(out_row + half * 8);
        o4[0] = make_float4(acc[0], acc[1], acc[2], acc[3]);
        o4[1] = make_float4(acc[4], acc[5], acc[6], acc[7]);
    }
}

// ---------------- EdgeConv 1: [6->16->16], u-precompute + reg-resident weights -----
__global__ __launch_bounds__(256) void conv1(
    const float* __restrict__ x,    // [NG*NN*3]
    const u16* __restrict__ idx,    // [NG*NN*16]
    const float* __restrict__ W1,   // [6*16]
    const float* __restrict__ b1,   // [16]
    const float* __restrict__ W2,   // [16*16]
    const float* __restrict__ b2,   // [16]
    float* __restrict__ h1)         // [NG*NN*16]
{
    __shared__ float u_lds[NN * 16];   // 64 KB: u[n][o] = sum_c x_n[c]*W1hi[c][o]

    const int g = blockIdx.x >> 2;
    const int chunk = blockIdx.x & 3;
    const int tid = threadIdx.x;

    float wlo[3][16], whi[3][16];      // 96 regs, prologue only
#pragma unroll
    for (int c = 0; c < 3; ++c) {
#pragma unroll
        for (int q = 0; q < 4; ++q) {
            *(float4*)&wlo[c][q * 4] = *(const float4*)(W1 + c * 16 + q * 4);
            *(float4*)&whi[c][q * 4] = *(const float4*)(W1 + (3 + c) * 16 + q * 4);
        }
    }

    // u rows (4 per thread)
#pragma unroll 1
    for (int r = 0; r < 4; ++r) {
        const int n = r * 256 + tid;
        const float* xp = x + ((size_t)g * NN + n) * 3;
        float px = xp[0], py = xp[1], pz = xp[2];
        float4* un = (float4*)(u_lds + n * 16);
#pragma unroll
        for (int q = 0; q < 4; ++q) {
            float4 uv;
            uv.x = px * whi[0][q * 4 + 0] + py * whi[1][q * 4 + 0] + pz * whi[2][q * 4 + 0];
            uv.y = px * whi[0][q * 4 + 1] + py * whi[1][q * 4 + 1] + pz * whi[2][q * 4 + 1];
            uv.z = px * whi[0][q * 4 + 2] + py * whi[1][q * 4 + 2] + pz * whi[2][q * 4 + 2];
            uv.w = px * whi[0][q * 4 + 3] + py * whi[1][q * 4 + 3] + pz * whi[2][q * 4 + 3];
            un[q] = uv;
        }
    }

    const int i = chunk * 256 + tid;
    const float* mp = x + ((size_t)g * NN + i) * 3;
    const float mxx = mp[0], myy = mp[1], mzz = mp[2];
    float s1[16];
#pragma unroll
    for (int o = 0; o < 16; ++o) {
        s1[o] = b1[o] + mxx * (wlo[0][o] - whi[0][o])
                      + myy * (wlo[1][o] - whi[1][o])
                      + mzz * (wlo[2][o] - whi[2][o]);
    }
    __syncthreads();

    edge_pass(u_lds, s1, idx + (size_t)(g * NN + i) * KK, W2, b2,
              h1 + (size_t)(g * NN + i) * 16);
}

// ---------------- EdgeConv 2: [32->16->16], in-place u over the h1 LDS tile --------
__global__ __launch_bounds__(256) void conv2(
    const float* __restrict__ h1,   // [NG*NN*16]
    const u16* __restrict__ idx,    // [NG*NN*16]
    const float* __restrict__ W1,   // [32*16]
    const float* __restrict__ b1,   // [16]
    const float* __restrict__ W2,   // [16*16]
    const float* __restrict__ b2,   // [16]
    float* __restrict__ h2)         // [NG*NN*16]
{
    __shared__ float tile[NN * 16];    // 64 KB: h1 rows, overwritten in place by u rows
    __shared__ float w1s[32 * 16];     // 2 KB staged W1
    __shared__ float b1s[16];

    const int g = blockIdx.x >> 2;
    const int chunk = blockIdx.x & 3;
    const int tid = threadIdx.x;

    w1s[tid] = W1[tid];
    w1s[256 + tid] = W1[256 + tid];
    if (tid < 16) b1s[tid] = b1[tid];

    float4* t4 = (float4*)tile;
    const float4* src4 = (const float4*)(h1 + (size_t)g * NN * 16);
    for (int t = tid; t < NN * 4; t += 256) t4[t] = src4[t];
    __syncthreads();

    float s1[16];
    // u-phase: each thread owns rows n = r*256+tid (reads & writes only its own rows,
    // so in-place is race-free). Memory clobber stops LICM from hoisting the 512
    // w1s values out of the r-loop (the round-8 spill source).
#pragma unroll 1
    for (int r = 0; r < 4; ++r) {
        asm volatile("" ::: "memory");
        const int n = r * 256 + tid;
        float4 x0 = t4[n * 4 + 0], x1 = t4[n * 4 + 1];
        float4 x2 = t4[n * 4 + 2], x3 = t4[n * 4 + 3];
        float xr[16] = {x0.x, x0.y, x0.z, x0.w, x1.x, x1.y, x1.z, x1.w,
                        x2.x, x2.y, x2.z, x2.w, x3.x, x3.y, x3.z, x3.w};
        float uo[16];
#pragma unroll
        for (int og = 0; og < 4; ++og) {
            float a0 = 0.f, a1 = 0.f, a2 = 0.f, a3 = 0.f;
#pragma unroll
            for (int f = 0; f < 16; ++f) {
                float4 wv = *(const float4*)(w1s + (16 + f) * 16 + og * 4);
                a0 += xr[f] * wv.x; a1 += xr[f] * wv.y;
                a2 += xr[f] * wv.z; a3 += xr[f] * wv.w;
            }
            uo[og * 4 + 0] = a0; uo[og * 4 + 1] = a1;
            uo[og * 4 + 2] = a2; uo[og * 4 + 3] = a3;
        }
        if (r == chunk) {              // uniform branch: this row is my own node i
            float t1[16];
#pragma unroll
            for (int og = 0; og < 4; ++og) {
                float a0 = 0.f, a1 = 0.f, a2 = 0.f, a3 = 0.f;
#pragma unroll
                for (int f = 0; f < 16; ++f) {
                    float4 wv = *(const float4*)(w1s + f * 16 + og * 4);
                    a0 += xr[f] * wv.x; a1 += xr[f] * wv.y;
                    a2 += xr[f] * wv.z; a3 += xr[f] * wv.w;
                }
                t1[og * 4 + 0] = a0; t1[og * 4 + 1] = a1;
                t1[og * 4 + 2] = a2; t1[og * 4 + 3] = a3;
            }
#pragma unroll
            for (int o = 0; o < 16; ++o) s1[o] = b1s[o] + t1[o] - uo[o];
        }
        t4[n * 4 + 0] = make_float4(uo[0], uo[1], uo[2], uo[3]);
        t4[n * 4 + 1] = make_float4(uo[4], uo[5], uo[6], uo[7]);
        t4[n * 4 + 2] = make_float4(uo[8], uo[9], uo[10], uo[11]);
        t4[n * 4 + 3] = make_float4(uo[12], uo[13], uo[14], uo[15]);
    }
    __syncthreads();

    const int i = chunk * 256 + tid;
    edge_pass(tile, s1, idx + (size_t)(g * NN + i) * KK, W2, b2,
              h2 + (size_t)(g * NN + i) * 16);
}

// ---------- Post-MLP [35->16->16] + block-partial pooling --------------------------
__global__ __launch_bounds__(256) void post_pool(
    const float* __restrict__ x,
    const float* __restrict__ h1,
    const float* __restrict__ h2,
    const float* __restrict__ Wp1, const float* __restrict__ bp1,
    const float* __restrict__ Wp2, const float* __restrict__ bp2,
    float* __restrict__ partial)
{
    __shared__ float wp1[35 * 16];
    __shared__ float wp2[16 * 16];
    __shared__ float sbp1[16], sbp2[16];
    __shared__ float red[3][4][16];

    const int g = blockIdx.x >> 2;
    const int chunk = blockIdx.x & 3;
    const int tid = threadIdx.x;

    wp2[tid] = Wp2[tid];
    for (int t = tid; t < 560; t += 256) wp1[t] = Wp1[t];
    if (tid < 16) { sbp1[tid] = bp1[tid]; sbp2[tid] = bp2[tid]; }
    __syncthreads();

    const int i = chunk * 256 + tid;
    const float* xp = x + (size_t)(g * NN + i) * 3;
    const float x0 = xp[0], x1 = xp[1], x2 = xp[2];
    const float4* p1v = (const float4*)(h1 + (size_t)(g * NN + i) * 16);
    float4 a0 = p1v[0], a1 = p1v[1], a2 = p1v[2], a3 = p1v[3];
    const float4* p2v = (const float4*)(h2 + (size_t)(g * NN + i) * 16);
    float4 c0 = p2v[0], c1 = p2v[1], c2 = p2v[2], c3 = p2v[3];

    float p1[16];
#pragma unroll
    for (int o = 0; o < 16; ++o) {
        float v = sbp1[o];
        v += x0 * wp1[0 * 16 + o];
        v += x1 * wp1[1 * 16 + o];
        v += x2 * wp1[2 * 16 + o];
        v += a0.x * wp1[3 * 16 + o];   v += a0.y * wp1[4 * 16 + o];
        v += a0.z * wp1[5 * 16 + o];   v += a0.w * wp1[6 * 16 + o];
        v += a1.x * wp1[7 * 16 + o];   v += a1.y * wp1[8 * 16 + o];
        v += a1.z * wp1[9 * 16 + o];   v += a1.w * wp1[10 * 16 + o];
        v += a2.x * wp1[11 * 16 + o];  v += a2.y * wp1[12 * 16 + o];
        v += a2.z * wp1[13 * 16 + o];  v += a2.w * wp1[14 * 16 + o];
        v += a3.x * wp1[15 * 16 + o];  v += a3.y * wp1[16 * 16 + o];
        v += a3.z * wp1[17 * 16 + o];  v += a3.w * wp1[18 * 16 + o];
        v += c0.x * wp1[19 * 16 + o];  v += c0.y * wp1[20 * 16 + o];
        v += c0.z * wp1[21 * 16 + o];  v += c0.w * wp1[22 * 16 + o];
        v += c1.x * wp1[23 * 16 + o];  v += c1.y * wp1[24 * 16 + o];
        v += c1.z * wp1[25 * 16 + o];  v += c1.w * wp1[26 * 16 + o];
        v += c2.x * wp1[27 * 16 + o];  v += c2.y * wp1[28 * 16 + o];
        v += c2.z * wp1[29 * 16 + o];  v += c2.w * wp1[30 * 16 + o];
        v += c3.x * wp1[31 * 16 + o];  v += c3.y * wp1[32 * 16 + o];
        v += c3.z * wp1[33 * 16 + o];  v += c3.w * wp1[34 * 16 + o];
        p1[o] = leaky(v);
    }

    float mn[16], mx[16], sm[16];
#pragma unroll
    for (int o = 0; o < 16; ++o) {
        float v = sbp2[o];
#pragma unroll
        for (int f = 0; f < 16; ++f) v += p1[f] * wp2[f * 16 + o];
        float p2 = leaky(v);
        mn[o] = p2; mx[o] = p2; sm[o] = p2;
    }

#pragma unroll
    for (int off = 32; off >= 1; off >>= 1) {
#pragma unroll
        for (int o = 0; o < 16; ++o) {
            mn[o] = fminf(mn[o], __shfl_xor(mn[o], off));
            mx[o] = fmaxf(mx[o], __shfl_xor(mx[o], off));
            sm[o] += __shfl_xor(sm[o], off);
        }
    }
    const int wave = tid >> 6;
    const int lane = tid & 63;
    if (lane == 0) {
#pragma unroll
        for (int o = 0; o < 16; ++o) {
            red[0][wave][o] = mn[o];
            red[1][wave][o] = mx[o];
            red[2][wave][o] = sm[o];
        }
    }
    __syncthreads();

    if (tid < 48) {
        const int stat = tid >> 4, o = tid & 15;
        float v;
        if (stat == 0)
            v = fminf(fminf(red[0][0][o], red[0][1][o]), fminf(red[0][2][o], red[0][3][o]));
        else if (stat == 1)
            v = fmaxf(fmaxf(red[1][0][o], red[1][1][o]), fmaxf(red[1][2][o], red[1][3][o]));
        else
            v = red[2][0][o] + red[2][1][o] + red[2][2][o] + red[2][3][o];
        partial[blockIdx.x * 48 + tid] = v;
    }
}

// -------- Finalize: combine 4 block-partials per graph + readout [48->128->10] -----
__global__ __launch_bounds__(128) void finalize(
    const float* __restrict__ partial,
    const float* __restrict__ Wr1, const float* __restrict__ br1,
    const float* __restrict__ Wr2, const float* __restrict__ br2,
    float* __restrict__ out)
{
    __shared__ float pooled[48];
    __shared__ float hidden[128];

    const int g = blockIdx.x;
    const int tid = threadIdx.x;

    if (tid < 48) {
        const int stat = tid >> 4;
        float a = partial[(g * 4 + 0) * 48 + tid];
        float b = partial[(g * 4 + 1) * 48 + tid];
        float c = partial[(g * 4 + 2) * 48 + tid];
        float d = partial[(g * 4 + 3) * 48 + tid];
        float v;
        if (stat == 0)      v = fminf(fminf(a, b), fminf(c, d));
        else if (stat == 1) v = fmaxf(fmaxf(a, b), fmaxf(c, d));
        else                v = (a + b + c + d) * (1.0f / NN);
        pooled[tid] = v;
    }
    __syncthreads();

    {
        float v = br1[tid];
#pragma unroll
        for (int f = 0; f < 48; ++f) v += pooled[f] * Wr1[f * 128 + tid];
        hidden[tid] = leaky(v);
    }
    __syncthreads();

    if (tid < 10) {
        float v = br2[tid];
#pragma unroll
        for (int f = 0; f < 128; ++f) v += hidden[f] * Wr2[f * 10 + tid];
        out[g * 10 + tid] = v;
    }
}

extern "C" void kernel_launch(void* const* d_in, const int* in_sizes, int n_in,
                              void* d_out, int out_size, void* d_ws, size_t ws_size,
                              hipStream_t stream) {
    const float* x   = (const float*)d_in[0];
    const float* W1a = (const float*)d_in[2];
    const float* b1a = (const float*)d_in[3];
    const float* W2a = (const float*)d_in[4];
    const float* b2a = (const float*)d_in[5];
    const float* W1b = (const float*)d_in[6];
    const float* b1b = (const float*)d_in[7];
    const float* W2b = (const float*)d_in[8];
    const float* b2b = (const float*)d_in[9];
    const float* Wp1 = (const float*)d_in[10];
    const float* bp1 = (const float*)d_in[11];
    const float* Wp2 = (const float*)d_in[12];
    const float* bp2 = (const float*)d_in[13];
    const float* Wr1 = (const float*)d_in[14];
    const float* br1 = (const float*)d_in[15];
    const float* Wr2 = (const float*)d_in[16];
    const float* br2 = (const float*)d_in[17];
    float* out = (float*)d_out;

    float* h1 = (float*)d_ws;                         // 8 MB
    float* h2 = h1 + (size_t)NG * NN * 16;            // 8 MB
    u16* idx = (u16*)(h2 + (size_t)NG * NN * 16);     // 4 MB (reused by both kNNs)
    float* partial = (float*)(idx + (size_t)NG * NN * KK);  // 512*48 floats

    knn1<<<NG * 4, 256, 0, stream>>>(x, idx);
    conv1<<<NG * 4, 256, 0, stream>>>(x, idx, W1a, b1a, W2a, b2a, h1);
    knn2<<<NG * 4, 256, 0, stream>>>(h1, idx);
    conv2<<<NG * 4, 256, 0, stream>>>(h1, idx, W1b, b1b, W2b, b2b, h2);
    post_pool<<<NG * 4, 256, 0, stream>>>(x, h1, h2, Wp1, bp1, Wp2, bp2, partial);
    finalize<<<NG, 128, 0, stream>>>(partial, Wr1, br1, Wr2, br2, out);
}